// Round 1
// baseline (544.522 us; speedup 1.0000x reference)
//
#include <hip/hip_runtime.h>

// GCN 2-layer: out = S·relu(S·(X·W1)+b1)·W2 + b2, S = sym-norm adj + self loops.
// N=100000 nodes, E=1600000 edges, D: 128 -> 128 -> 64, all fp32.

#define D_IN  128
#define D_HID 128
#define D_OUT 64

// ---------------- graph prep ----------------

__global__ __launch_bounds__(256) void k_zero_int(int* __restrict__ p, int n) {
    int i = blockIdx.x * 256 + threadIdx.x;
    if (i < n) p[i] = 0;
}

__global__ __launch_bounds__(256) void k_count(const int* __restrict__ dst,
                                               int* __restrict__ cnt, int E) {
    int i = blockIdx.x * 256 + threadIdx.x;
    if (i < E) atomicAdd(&cnt[dst[i]], 1);
}

__global__ __launch_bounds__(256) void k_dinv(const int* __restrict__ cnt,
                                              float* __restrict__ dinv, int N) {
    int i = blockIdx.x * 256 + threadIdx.x;
    if (i < N) dinv[i] = rsqrtf((float)(cnt[i] + 1));  // +1 self loop, deg >= 1
}

// exclusive scan of cnt[N] -> rowstart[N]; 1024 elems/block (256 thr x 4)
__global__ __launch_bounds__(256) void k_scan1(const int* __restrict__ cnt,
                                               int* __restrict__ rowstart,
                                               int* __restrict__ blockSums, int N) {
    __shared__ int ls[256];
    const int t = threadIdx.x;
    const int base = blockIdx.x * 1024;
    int v[4], s = 0;
#pragma unroll
    for (int i = 0; i < 4; ++i) {
        int idx = base + t * 4 + i;
        v[i] = (idx < N) ? cnt[idx] : 0;
        s += v[i];
    }
    ls[t] = s;
    __syncthreads();
    for (int off = 1; off < 256; off <<= 1) {
        int y = (t >= off) ? ls[t - off] : 0;
        __syncthreads();
        ls[t] += y;
        __syncthreads();
    }
    int excl = ls[t] - s;   // exclusive prefix of this thread within block
    int run = excl;
#pragma unroll
    for (int i = 0; i < 4; ++i) {
        int idx = base + t * 4 + i;
        if (idx < N) rowstart[idx] = run;
        run += v[i];
    }
    if (t == 255) blockSums[blockIdx.x] = ls[255];
}

// exclusive scan of blockSums (nb <= 256), single block of 256
__global__ __launch_bounds__(256) void k_scan2(int* __restrict__ blockSums, int nb) {
    __shared__ int ls[256];
    const int t = threadIdx.x;
    int v = (t < nb) ? blockSums[t] : 0;
    ls[t] = v;
    __syncthreads();
    for (int off = 1; off < 256; off <<= 1) {
        int y = (t >= off) ? ls[t - off] : 0;
        __syncthreads();
        ls[t] += y;
        __syncthreads();
    }
    if (t < nb) blockSums[t] = ls[t] - v;  // exclusive
}

__global__ __launch_bounds__(256) void k_scan3(int* __restrict__ rowstart,
                                               int* __restrict__ cursor,
                                               const int* __restrict__ blockSums,
                                               int N, int E) {
    int i = blockIdx.x * 256 + threadIdx.x;
    if (i < N) {
        int v = rowstart[i] + blockSums[i >> 10];
        rowstart[i] = v;
        cursor[i] = v;
    }
    if (i == 0) rowstart[N] = E;
}

__global__ __launch_bounds__(256) void k_fill(const int* __restrict__ src,
                                              const int* __restrict__ dst,
                                              int* __restrict__ cursor,
                                              int* __restrict__ csr_src, int E) {
    int e = blockIdx.x * 256 + threadIdx.x;
    if (e < E) {
        int pos = atomicAdd(&cursor[dst[e]], 1);
        csr_src[pos] = src[e];
    }
}

// ---------------- fp32 GEMM: H[N,DOUT] = X[N,128] @ W[128,DOUT] ----------------
// Tile: 64 rows x DOUT cols per block of 256 threads. W resident in LDS,
// X k-chunked (KC=32) through LDS with +1 padding. Register block RPT x 4.

template <int DOUT>
__global__ __launch_bounds__(256) void gemm_kernel(const float* __restrict__ X,
                                                   const float* __restrict__ W,
                                                   float* __restrict__ H, int N) {
    constexpr int K = 128;
    constexpr int TR = 64;
    constexpr int KC = 32;
    constexpr int CPT = 4;
    constexpr int CG = DOUT / CPT;      // 32 (D=128) or 16 (D=64)
    constexpr int TROWS = 256 / CG;     // 8 or 16
    constexpr int RPT = TR / TROWS;     // 8 or 4

    __shared__ float Ws[K][DOUT];
    __shared__ float Xs[TR][KC + 1];

    const int t = threadIdx.x;
    const int cg = t % CG;
    const int tr = t / CG;
    const int colbase = cg * CPT;
    const int rowbase = tr * RPT;
    const int block_row0 = blockIdx.x * TR;

    for (int i = t; i < K * DOUT; i += 256) Ws[i / DOUT][i % DOUT] = W[i];

    float acc[RPT][CPT];
#pragma unroll
    for (int r = 0; r < RPT; ++r)
#pragma unroll
        for (int c = 0; c < CPT; ++c) acc[r][c] = 0.f;

    for (int k0 = 0; k0 < K; k0 += KC) {
        __syncthreads();  // also covers initial Ws fill
        for (int i = t; i < TR * (KC / 4); i += 256) {
            int r = i / (KC / 4);
            int c4 = i % (KC / 4);
            int grow = block_row0 + r;
            float4 v = make_float4(0.f, 0.f, 0.f, 0.f);
            if (grow < N)
                v = *reinterpret_cast<const float4*>(&X[(size_t)grow * K + k0 + c4 * 4]);
            Xs[r][c4 * 4 + 0] = v.x;
            Xs[r][c4 * 4 + 1] = v.y;
            Xs[r][c4 * 4 + 2] = v.z;
            Xs[r][c4 * 4 + 3] = v.w;
        }
        __syncthreads();
#pragma unroll
        for (int kk = 0; kk < KC; ++kk) {
            float wv[CPT];
#pragma unroll
            for (int c = 0; c < CPT; ++c) wv[c] = Ws[k0 + kk][colbase + c];
#pragma unroll
            for (int r = 0; r < RPT; ++r) {
                float xv = Xs[rowbase + r][kk];
#pragma unroll
                for (int c = 0; c < CPT; ++c) acc[r][c] = fmaf(xv, wv[c], acc[r][c]);
            }
        }
    }

#pragma unroll
    for (int r = 0; r < RPT; ++r) {
        int grow = block_row0 + rowbase + r;
        if (grow < N) {
            float4 v = make_float4(acc[r][0], acc[r][1], acc[r][2], acc[r][3]);
            *reinterpret_cast<float4*>(&H[(size_t)grow * DOUT + colbase]) = v;
        }
    }
}

// ---------------- CSR pull aggregation ----------------
// One wave per node. out[n] = sum_{s in in(n)} H[s]*dinv[s]*dinv[n]
//                           + H[n]*dinv[n]^2 + bias  (optional relu)

template <int D, bool RELU>
__global__ __launch_bounds__(256) void agg_kernel(const float* __restrict__ H,
                                                  const int* __restrict__ rowstart,
                                                  const int* __restrict__ csr_src,
                                                  const float* __restrict__ dinv,
                                                  const float* __restrict__ bias,
                                                  float* __restrict__ out, int N) {
    const int wid = (blockIdx.x * 256 + threadIdx.x) >> 6;  // node id
    const int lane = threadIdx.x & 63;
    if (wid >= N) return;
    const int n = wid;
    const float dn = dinv[n];
    const int e0 = rowstart[n], e1 = rowstart[n + 1];

    if (D == 128) {
        float2 acc = make_float2(0.f, 0.f);
        for (int eb = e0; eb < e1; eb += 64) {
            int myE = eb + lane;
            int s_l = (myE < e1) ? csr_src[myE] : 0;
            float w_l = (myE < e1) ? dinv[s_l] * dn : 0.f;
            int nbatch = min(64, e1 - eb);
            for (int i = 0; i < nbatch; ++i) {
                int s = __shfl(s_l, i);
                float w = __shfl(w_l, i);
                float2 v = *reinterpret_cast<const float2*>(&H[(size_t)s * D + lane * 2]);
                acc.x = fmaf(v.x, w, acc.x);
                acc.y = fmaf(v.y, w, acc.y);
            }
        }
        float2 vs = *reinterpret_cast<const float2*>(&H[(size_t)n * D + lane * 2]);
        float ws = dn * dn;
        acc.x = fmaf(vs.x, ws, acc.x) + bias[lane * 2 + 0];
        acc.y = fmaf(vs.y, ws, acc.y) + bias[lane * 2 + 1];
        if (RELU) {
            acc.x = fmaxf(acc.x, 0.f);
            acc.y = fmaxf(acc.y, 0.f);
        }
        *reinterpret_cast<float2*>(&out[(size_t)n * D + lane * 2]) = acc;
    } else {
        float acc = 0.f;
        for (int eb = e0; eb < e1; eb += 64) {
            int myE = eb + lane;
            int s_l = (myE < e1) ? csr_src[myE] : 0;
            float w_l = (myE < e1) ? dinv[s_l] * dn : 0.f;
            int nbatch = min(64, e1 - eb);
            for (int i = 0; i < nbatch; ++i) {
                int s = __shfl(s_l, i);
                float w = __shfl(w_l, i);
                acc = fmaf(H[(size_t)s * D + lane], w, acc);
            }
        }
        acc = fmaf(H[(size_t)n * D + lane], dn * dn, acc) + bias[lane];
        if (RELU) acc = fmaxf(acc, 0.f);
        out[(size_t)n * D + lane] = acc;
    }
}

// ---------------- launch ----------------

extern "C" void kernel_launch(void* const* d_in, const int* in_sizes, int n_in,
                              void* d_out, int out_size, void* d_ws, size_t ws_size,
                              hipStream_t stream) {
    const float* x  = (const float*)d_in[0];
    const int*   ei = (const int*)d_in[1];
    const float* W1 = (const float*)d_in[2];
    const float* b1 = (const float*)d_in[3];
    const float* W2 = (const float*)d_in[4];
    const float* b2 = (const float*)d_in[5];
    float* out = (float*)d_out;

    const int N = in_sizes[0] / D_IN;
    const int E = in_sizes[1] / 2;
    const int* src = ei;
    const int* dst = ei + E;

    char* w = (char*)d_ws;
    auto alloc = [&](size_t bytes) {
        char* p = w;
        w += (bytes + 255) & ~(size_t)255;
        return p;
    };
    int*   cnt       = (int*)alloc((size_t)N * 4);
    int*   rowstart  = (int*)alloc((size_t)(N + 1) * 4);
    int*   cursor    = (int*)alloc((size_t)N * 4);
    int*   blockSums = (int*)alloc(256 * 4);
    float* dinv      = (float*)alloc((size_t)N * 4);
    int*   csr       = (int*)alloc((size_t)E * 4);
    float* h1        = (float*)alloc((size_t)N * D_HID * 4);
    float* hg        = (float*)alloc((size_t)N * D_HID * 4);
    float* h2        = h1;  // reuse: h1 dead after agg1

    const int nb = (N + 1023) / 1024;

    k_zero_int<<<(N + 255) / 256, 256, 0, stream>>>(cnt, N);
    k_count<<<(E + 255) / 256, 256, 0, stream>>>(dst, cnt, E);
    k_dinv<<<(N + 255) / 256, 256, 0, stream>>>(cnt, dinv, N);
    k_scan1<<<nb, 256, 0, stream>>>(cnt, rowstart, blockSums, N);
    k_scan2<<<1, 256, 0, stream>>>(blockSums, nb);
    k_scan3<<<(N + 255) / 256, 256, 0, stream>>>(rowstart, cursor, blockSums, N, E);
    k_fill<<<(E + 255) / 256, 256, 0, stream>>>(src, dst, cursor, csr, E);

    gemm_kernel<D_HID><<<(N + 63) / 64, 256, 0, stream>>>(x, W1, h1, N);
    agg_kernel<D_HID, true><<<(N + 3) / 4, 256, 0, stream>>>(h1, rowstart, csr, dinv, b1, hg, N);
    gemm_kernel<D_OUT><<<(N + 63) / 64, 256, 0, stream>>>(hg, W2, h2, N);
    agg_kernel<D_OUT, false><<<(N + 3) / 4, 256, 0, stream>>>(h2, rowstart, csr, dinv, b2, out, N);
}

// Round 2
// 458.472 us; speedup vs baseline: 1.1877x; 1.1877x over previous
//
#include <hip/hip_runtime.h>

// GCN 2-layer: out = S·relu(S·(X·W1)+b1)·W2 + b2, S = sym-norm adj + self loops.
// N=100000 nodes, E=1600000 edges, D: 128 -> 128 -> 64, all fp32.

#define D_IN  128
#define D_HID 128
#define D_OUT 64

// ---------------- graph prep ----------------

__global__ __launch_bounds__(256) void k_zero_int(int* __restrict__ p, int n) {
    int i = blockIdx.x * 256 + threadIdx.x;
    if (i < n) p[i] = 0;
}

__global__ __launch_bounds__(256) void k_count(const int* __restrict__ dst,
                                               int* __restrict__ cnt, int E) {
    int i = blockIdx.x * 256 + threadIdx.x;
    if (i < E) atomicAdd(&cnt[dst[i]], 1);
}

__global__ __launch_bounds__(256) void k_dinv(const int* __restrict__ cnt,
                                              float* __restrict__ dinv, int N) {
    int i = blockIdx.x * 256 + threadIdx.x;
    if (i < N) dinv[i] = rsqrtf((float)(cnt[i] + 1));  // +1 self loop, deg >= 1
}

// exclusive scan of cnt[N] -> rowstart[N]; 1024 elems/block (256 thr x 4)
__global__ __launch_bounds__(256) void k_scan1(const int* __restrict__ cnt,
                                               int* __restrict__ rowstart,
                                               int* __restrict__ blockSums, int N) {
    __shared__ int ls[256];
    const int t = threadIdx.x;
    const int base = blockIdx.x * 1024;
    int v[4], s = 0;
#pragma unroll
    for (int i = 0; i < 4; ++i) {
        int idx = base + t * 4 + i;
        v[i] = (idx < N) ? cnt[idx] : 0;
        s += v[i];
    }
    ls[t] = s;
    __syncthreads();
    for (int off = 1; off < 256; off <<= 1) {
        int y = (t >= off) ? ls[t - off] : 0;
        __syncthreads();
        ls[t] += y;
        __syncthreads();
    }
    int excl = ls[t] - s;
    int run = excl;
#pragma unroll
    for (int i = 0; i < 4; ++i) {
        int idx = base + t * 4 + i;
        if (idx < N) rowstart[idx] = run;
        run += v[i];
    }
    if (t == 255) blockSums[blockIdx.x] = ls[255];
}

__global__ __launch_bounds__(256) void k_scan2(int* __restrict__ blockSums, int nb) {
    __shared__ int ls[256];
    const int t = threadIdx.x;
    int v = (t < nb) ? blockSums[t] : 0;
    ls[t] = v;
    __syncthreads();
    for (int off = 1; off < 256; off <<= 1) {
        int y = (t >= off) ? ls[t - off] : 0;
        __syncthreads();
        ls[t] += y;
        __syncthreads();
    }
    if (t < nb) blockSums[t] = ls[t] - v;  // exclusive
}

__global__ __launch_bounds__(256) void k_scan3(int* __restrict__ rowstart,
                                               int* __restrict__ cursor,
                                               const int* __restrict__ blockSums,
                                               int N, int E) {
    int i = blockIdx.x * 256 + threadIdx.x;
    if (i < N) {
        int v = rowstart[i] + blockSums[i >> 10];
        rowstart[i] = v;
        cursor[i] = v;
    }
    if (i == 0) rowstart[N] = E;
}

__global__ __launch_bounds__(256) void k_fill(const int* __restrict__ src,
                                              const int* __restrict__ dst,
                                              int* __restrict__ cursor,
                                              int* __restrict__ csr_src, int E) {
    int e = blockIdx.x * 256 + threadIdx.x;
    if (e < E) {
        int pos = atomicAdd(&cursor[dst[e]], 1);
        csr_src[pos] = src[e];
    }
}

// ---------------- fp32 GEMM: H[N,DOUT] = X[N,128] @ W[128,DOUT] ----------------
// 64 rows x DOUT cols per block of 256 threads. W k-chunked through LDS
// (16 KB for D=128 -> ~6 blocks/CU vs 2 before). All LDS reads are float4.

template <int DOUT>
__global__ __launch_bounds__(256) void gemm_kernel(const float* __restrict__ X,
                                                   const float* __restrict__ W,
                                                   float* __restrict__ H, int N) {
    constexpr int K = 128;
    constexpr int TR = 64;
    constexpr int KC = 32;
    constexpr int CPT = 4;
    constexpr int CG = DOUT / CPT;      // 32 (D=128) or 16 (D=64)
    constexpr int TROWS = 256 / CG;     // 8 or 16
    constexpr int RPT = TR / TROWS;     // 8 or 4
    constexpr int XP = KC + 4;          // keep float4 alignment (144B row)

    __shared__ float Ws[KC][DOUT];
    __shared__ float Xs[TR][XP];

    const int t = threadIdx.x;
    const int cg = t % CG;
    const int tr = t / CG;
    const int colbase = cg * CPT;
    const int rowbase = tr * RPT;
    const int block_row0 = blockIdx.x * TR;

    float acc[RPT][CPT];
#pragma unroll
    for (int r = 0; r < RPT; ++r)
#pragma unroll
        for (int c = 0; c < CPT; ++c) acc[r][c] = 0.f;

    for (int k0 = 0; k0 < K; k0 += KC) {
        __syncthreads();
        // stage W chunk [KC][DOUT], float4, fully coalesced
        for (int i = t * 4; i < KC * DOUT; i += 256 * 4) {
            int kk = i / DOUT, c = i % DOUT;
            *reinterpret_cast<float4*>(&Ws[kk][c]) =
                *reinterpret_cast<const float4*>(&W[(size_t)(k0 + kk) * DOUT + c]);
        }
        // stage X tile [TR][KC]
        for (int i = t; i < TR * (KC / 4); i += 256) {
            int r = i / (KC / 4), c4 = (i % (KC / 4)) * 4;
            int grow = block_row0 + r;
            float4 v = make_float4(0.f, 0.f, 0.f, 0.f);
            if (grow < N)
                v = *reinterpret_cast<const float4*>(&X[(size_t)grow * K + k0 + c4]);
            *reinterpret_cast<float4*>(&Xs[r][c4]) = v;
        }
        __syncthreads();
#pragma unroll
        for (int kk = 0; kk < KC; kk += 4) {
            float4 wv[4];
#pragma unroll
            for (int q = 0; q < 4; ++q)
                wv[q] = *reinterpret_cast<const float4*>(&Ws[kk + q][colbase]);
#pragma unroll
            for (int r = 0; r < RPT; ++r) {
                float4 xv = *reinterpret_cast<const float4*>(&Xs[rowbase + r][kk]);
                acc[r][0] = fmaf(xv.x, wv[0].x, acc[r][0]);
                acc[r][1] = fmaf(xv.x, wv[0].y, acc[r][1]);
                acc[r][2] = fmaf(xv.x, wv[0].z, acc[r][2]);
                acc[r][3] = fmaf(xv.x, wv[0].w, acc[r][3]);
                acc[r][0] = fmaf(xv.y, wv[1].x, acc[r][0]);
                acc[r][1] = fmaf(xv.y, wv[1].y, acc[r][1]);
                acc[r][2] = fmaf(xv.y, wv[1].z, acc[r][2]);
                acc[r][3] = fmaf(xv.y, wv[1].w, acc[r][3]);
                acc[r][0] = fmaf(xv.z, wv[2].x, acc[r][0]);
                acc[r][1] = fmaf(xv.z, wv[2].y, acc[r][1]);
                acc[r][2] = fmaf(xv.z, wv[2].z, acc[r][2]);
                acc[r][3] = fmaf(xv.z, wv[2].w, acc[r][3]);
                acc[r][0] = fmaf(xv.w, wv[3].x, acc[r][0]);
                acc[r][1] = fmaf(xv.w, wv[3].y, acc[r][1]);
                acc[r][2] = fmaf(xv.w, wv[3].z, acc[r][2]);
                acc[r][3] = fmaf(xv.w, wv[3].w, acc[r][3]);
            }
        }
    }

#pragma unroll
    for (int r = 0; r < RPT; ++r) {
        int grow = block_row0 + rowbase + r;
        if (grow < N) {
            float4 v = make_float4(acc[r][0], acc[r][1], acc[r][2], acc[r][3]);
            *reinterpret_cast<float4*>(&H[(size_t)grow * DOUT + colbase]) = v;
        }
    }
}

// ---------------- CSR pull aggregation ----------------
// One wave per node; 8-deep software pipeline: batch-broadcast 8 edges,
// issue 8 gathers, then 8 FMAs. Tail padded with w=0 lanes (gather row 0,
// L1-hit, multiply-by-zero) -> no branches in the hot loop.

template <int D, bool RELU>
__global__ __launch_bounds__(256) void agg_kernel(const float* __restrict__ H,
                                                  const int* __restrict__ rowstart,
                                                  const int* __restrict__ csr_src,
                                                  const float* __restrict__ dinv,
                                                  const float* __restrict__ bias,
                                                  float* __restrict__ out, int N) {
    const int wid = (blockIdx.x * 256 + threadIdx.x) >> 6;  // node id
    const int lane = threadIdx.x & 63;
    if (wid >= N) return;
    const float dn = dinv[wid];
    const int e0 = rowstart[wid], e1 = rowstart[wid + 1];

    if (D == 128) {
        const float2* __restrict__ H2 = reinterpret_cast<const float2*>(H);
        float accx = 0.f, accy = 0.f;
        for (int eb = e0; eb < e1; eb += 64) {
            int myE = eb + lane;
            bool valid = myE < e1;
            int s_l = valid ? csr_src[myE] : 0;
            float w_l = valid ? dinv[s_l] * dn : 0.f;
            int nbatch = min(64, e1 - eb);
            for (int i = 0; i < nbatch; i += 8) {
                int s[8]; float w[8]; float2 h[8];
#pragma unroll
                for (int j = 0; j < 8; ++j) {
                    s[j] = __shfl(s_l, i + j);
                    w[j] = __shfl(w_l, i + j);
                }
#pragma unroll
                for (int j = 0; j < 8; ++j) h[j] = H2[(size_t)s[j] * 64 + lane];
#pragma unroll
                for (int j = 0; j < 8; ++j) {
                    accx = fmaf(h[j].x, w[j], accx);
                    accy = fmaf(h[j].y, w[j], accy);
                }
            }
        }
        float2 vs = H2[(size_t)wid * 64 + lane];
        float ws = dn * dn;
        accx = fmaf(vs.x, ws, accx) + bias[lane * 2 + 0];
        accy = fmaf(vs.y, ws, accy) + bias[lane * 2 + 1];
        if (RELU) {
            accx = fmaxf(accx, 0.f);
            accy = fmaxf(accy, 0.f);
        }
        reinterpret_cast<float2*>(out)[(size_t)wid * 64 + lane] = make_float2(accx, accy);
    } else {
        float acc = 0.f;
        for (int eb = e0; eb < e1; eb += 64) {
            int myE = eb + lane;
            bool valid = myE < e1;
            int s_l = valid ? csr_src[myE] : 0;
            float w_l = valid ? dinv[s_l] * dn : 0.f;
            int nbatch = min(64, e1 - eb);
            for (int i = 0; i < nbatch; i += 8) {
                int s[8]; float w[8]; float h[8];
#pragma unroll
                for (int j = 0; j < 8; ++j) {
                    s[j] = __shfl(s_l, i + j);
                    w[j] = __shfl(w_l, i + j);
                }
#pragma unroll
                for (int j = 0; j < 8; ++j) h[j] = H[(size_t)s[j] * 64 + lane];
#pragma unroll
                for (int j = 0; j < 8; ++j) acc = fmaf(h[j], w[j], acc);
            }
        }
        acc = fmaf(H[(size_t)wid * 64 + lane], dn * dn, acc) + bias[lane];
        if (RELU) acc = fmaxf(acc, 0.f);
        out[(size_t)wid * 64 + lane] = acc;
    }
}

// ---------------- launch ----------------

extern "C" void kernel_launch(void* const* d_in, const int* in_sizes, int n_in,
                              void* d_out, int out_size, void* d_ws, size_t ws_size,
                              hipStream_t stream) {
    const float* x  = (const float*)d_in[0];
    const int*   ei = (const int*)d_in[1];
    const float* W1 = (const float*)d_in[2];
    const float* b1 = (const float*)d_in[3];
    const float* W2 = (const float*)d_in[4];
    const float* b2 = (const float*)d_in[5];
    float* out = (float*)d_out;

    const int N = in_sizes[0] / D_IN;
    const int E = in_sizes[1] / 2;
    const int* src = ei;
    const int* dst = ei + E;

    char* w = (char*)d_ws;
    auto alloc = [&](size_t bytes) {
        char* p = w;
        w += (bytes + 255) & ~(size_t)255;
        return p;
    };
    int*   cnt       = (int*)alloc((size_t)N * 4);
    int*   rowstart  = (int*)alloc((size_t)(N + 1) * 4);
    int*   cursor    = (int*)alloc((size_t)N * 4);
    int*   blockSums = (int*)alloc(256 * 4);
    float* dinv      = (float*)alloc((size_t)N * 4);
    int*   csr       = (int*)alloc((size_t)E * 4);
    float* h1        = (float*)alloc((size_t)N * D_HID * 4);
    float* hg        = (float*)alloc((size_t)N * D_HID * 4);
    float* h2        = h1;  // reuse: h1 dead after agg1

    const int nb = (N + 1023) / 1024;

    k_zero_int<<<(N + 255) / 256, 256, 0, stream>>>(cnt, N);
    k_count<<<(E + 255) / 256, 256, 0, stream>>>(dst, cnt, E);
    k_dinv<<<(N + 255) / 256, 256, 0, stream>>>(cnt, dinv, N);
    k_scan1<<<nb, 256, 0, stream>>>(cnt, rowstart, blockSums, N);
    k_scan2<<<1, 256, 0, stream>>>(blockSums, nb);
    k_scan3<<<(N + 255) / 256, 256, 0, stream>>>(rowstart, cursor, blockSums, N, E);
    k_fill<<<(E + 255) / 256, 256, 0, stream>>>(src, dst, cursor, csr, E);

    gemm_kernel<D_HID><<<(N + 63) / 64, 256, 0, stream>>>(x, W1, h1, N);
    agg_kernel<D_HID, true><<<(N + 3) / 4, 256, 0, stream>>>(h1, rowstart, csr, dinv, b1, hg, N);
    gemm_kernel<D_OUT><<<(N + 63) / 64, 256, 0, stream>>>(hg, W2, h2, N);
    agg_kernel<D_OUT, false><<<(N + 3) / 4, 256, 0, stream>>>(h2, rowstart, csr, dinv, b2, out, N);
}

// Round 3
// 387.559 us; speedup vs baseline: 1.4050x; 1.1830x over previous
//
#include <hip/hip_runtime.h>

// GCN 2-layer: out = S·relu(S·(X·W1)+b1)·W2 + b2, S = sym-norm adj + self loops.
// N=100000 nodes, E=1600000 edges, D: 128 -> 128 -> 64.
// Aggregation operand stored bf16 pre-scaled by dinv[src]; accumulate fp32.

#define D_IN  128
#define D_HID 128
#define D_OUT 64

__device__ __forceinline__ unsigned short f2bf(float f) {
    unsigned int u = __float_as_uint(f);
    u += 0x7fffu + ((u >> 16) & 1u);   // RNE
    return (unsigned short)(u >> 16);
}
__device__ __forceinline__ float bf_lo(unsigned int u) { return __uint_as_float(u << 16); }
__device__ __forceinline__ float bf_hi(unsigned int u) { return __uint_as_float(u & 0xffff0000u); }

// ---------------- graph prep ----------------

__global__ __launch_bounds__(256) void k_zero_int(int* __restrict__ p, int n) {
    int i = blockIdx.x * 256 + threadIdx.x;
    if (i < n) p[i] = 0;
}

__global__ __launch_bounds__(256) void k_count(const int* __restrict__ dst,
                                               int* __restrict__ cnt, int E) {
    int i = blockIdx.x * 256 + threadIdx.x;
    if (i < E) atomicAdd(&cnt[dst[i]], 1);
}

__global__ __launch_bounds__(256) void k_dinv(const int* __restrict__ cnt,
                                              float* __restrict__ dinv, int N) {
    int i = blockIdx.x * 256 + threadIdx.x;
    if (i < N) dinv[i] = rsqrtf((float)(cnt[i] + 1));  // +1 self loop
}

// exclusive scan of cnt[N] -> rowstart[N]; 1024 elems/block
__global__ __launch_bounds__(256) void k_scan1(const int* __restrict__ cnt,
                                               int* __restrict__ rowstart,
                                               int* __restrict__ blockSums, int N) {
    __shared__ int ls[256];
    const int t = threadIdx.x;
    const int base = blockIdx.x * 1024;
    int v[4], s = 0;
#pragma unroll
    for (int i = 0; i < 4; ++i) {
        int idx = base + t * 4 + i;
        v[i] = (idx < N) ? cnt[idx] : 0;
        s += v[i];
    }
    ls[t] = s;
    __syncthreads();
    for (int off = 1; off < 256; off <<= 1) {
        int y = (t >= off) ? ls[t - off] : 0;
        __syncthreads();
        ls[t] += y;
        __syncthreads();
    }
    int run = ls[t] - s;
#pragma unroll
    for (int i = 0; i < 4; ++i) {
        int idx = base + t * 4 + i;
        if (idx < N) rowstart[idx] = run;
        run += v[i];
    }
    if (t == 255) blockSums[blockIdx.x] = ls[255];
}

__global__ __launch_bounds__(256) void k_scan2(int* __restrict__ blockSums, int nb) {
    __shared__ int ls[256];
    const int t = threadIdx.x;
    int v = (t < nb) ? blockSums[t] : 0;
    ls[t] = v;
    __syncthreads();
    for (int off = 1; off < 256; off <<= 1) {
        int y = (t >= off) ? ls[t - off] : 0;
        __syncthreads();
        ls[t] += y;
        __syncthreads();
    }
    if (t < nb) blockSums[t] = ls[t] - v;  // exclusive
}

__global__ __launch_bounds__(256) void k_scan3(int* __restrict__ rowstart,
                                               int* __restrict__ cursor,
                                               const int* __restrict__ blockSums,
                                               int N, int E) {
    int i = blockIdx.x * 256 + threadIdx.x;
    if (i < N) {
        int v = rowstart[i] + blockSums[i >> 10];
        rowstart[i] = v;
        cursor[i] = v;
    }
    if (i == 0) rowstart[N] = E;
}

__global__ __launch_bounds__(256) void k_fill(const int* __restrict__ src,
                                              const int* __restrict__ dst,
                                              int* __restrict__ cursor,
                                              int* __restrict__ csr_src, int E) {
    int e = blockIdx.x * 256 + threadIdx.x;
    if (e < E) {
        int pos = atomicAdd(&cursor[dst[e]], 1);
        csr_src[pos] = src[e];
    }
}

// zero the pad row (index N) of both bf16 feature buffers
__global__ void k_zero_pad(unsigned short* __restrict__ h1b,
                           unsigned short* __restrict__ h2b, int N) {
    int t = threadIdx.x;
    if (t < 128) h1b[(size_t)N * 128 + t] = 0;
    if (t < 64)  h2b[(size_t)N * 64 + t] = 0;
}

// -------- fp32 GEMM: Hb[n,:] = bf16( (X[n,:]@W) * dinv[n] ), X:[N,128] --------

template <int DOUT>
__global__ __launch_bounds__(256) void gemm_kernel(const float* __restrict__ X,
                                                   const float* __restrict__ W,
                                                   const float* __restrict__ dinv,
                                                   unsigned short* __restrict__ Hb,
                                                   int N) {
    constexpr int K = 128;
    constexpr int TR = 64;
    constexpr int KC = 32;
    constexpr int CPT = 4;
    constexpr int CG = DOUT / CPT;      // 32 or 16
    constexpr int TROWS = 256 / CG;     // 8 or 16
    constexpr int RPT = TR / TROWS;     // 8 or 4
    constexpr int XP = KC + 4;

    __shared__ float Ws[KC][DOUT];
    __shared__ float Xs[TR][XP];

    const int t = threadIdx.x;
    const int cg = t % CG;
    const int tr = t / CG;
    const int colbase = cg * CPT;
    const int rowbase = tr * RPT;
    const int block_row0 = blockIdx.x * TR;

    float acc[RPT][CPT];
#pragma unroll
    for (int r = 0; r < RPT; ++r)
#pragma unroll
        for (int c = 0; c < CPT; ++c) acc[r][c] = 0.f;

    for (int k0 = 0; k0 < K; k0 += KC) {
        __syncthreads();
        for (int i = t * 4; i < KC * DOUT; i += 256 * 4) {
            int kk = i / DOUT, c = i % DOUT;
            *reinterpret_cast<float4*>(&Ws[kk][c]) =
                *reinterpret_cast<const float4*>(&W[(size_t)(k0 + kk) * DOUT + c]);
        }
        for (int i = t; i < TR * (KC / 4); i += 256) {
            int r = i / (KC / 4), c4 = (i % (KC / 4)) * 4;
            int grow = block_row0 + r;
            float4 v = make_float4(0.f, 0.f, 0.f, 0.f);
            if (grow < N)
                v = *reinterpret_cast<const float4*>(&X[(size_t)grow * K + k0 + c4]);
            *reinterpret_cast<float4*>(&Xs[r][c4]) = v;
        }
        __syncthreads();
#pragma unroll
        for (int kk = 0; kk < KC; kk += 4) {
            float4 wv[4];
#pragma unroll
            for (int q = 0; q < 4; ++q)
                wv[q] = *reinterpret_cast<const float4*>(&Ws[kk + q][colbase]);
#pragma unroll
            for (int r = 0; r < RPT; ++r) {
                float4 xv = *reinterpret_cast<const float4*>(&Xs[rowbase + r][kk]);
                acc[r][0] = fmaf(xv.x, wv[0].x, acc[r][0]);
                acc[r][1] = fmaf(xv.x, wv[0].y, acc[r][1]);
                acc[r][2] = fmaf(xv.x, wv[0].z, acc[r][2]);
                acc[r][3] = fmaf(xv.x, wv[0].w, acc[r][3]);
                acc[r][0] = fmaf(xv.y, wv[1].x, acc[r][0]);
                acc[r][1] = fmaf(xv.y, wv[1].y, acc[r][1]);
                acc[r][2] = fmaf(xv.y, wv[1].z, acc[r][2]);
                acc[r][3] = fmaf(xv.y, wv[1].w, acc[r][3]);
                acc[r][0] = fmaf(xv.z, wv[2].x, acc[r][0]);
                acc[r][1] = fmaf(xv.z, wv[2].y, acc[r][1]);
                acc[r][2] = fmaf(xv.z, wv[2].z, acc[r][2]);
                acc[r][3] = fmaf(xv.z, wv[2].w, acc[r][3]);
                acc[r][0] = fmaf(xv.w, wv[3].x, acc[r][0]);
                acc[r][1] = fmaf(xv.w, wv[3].y, acc[r][1]);
                acc[r][2] = fmaf(xv.w, wv[3].z, acc[r][2]);
                acc[r][3] = fmaf(xv.w, wv[3].w, acc[r][3]);
            }
        }
    }

#pragma unroll
    for (int r = 0; r < RPT; ++r) {
        int grow = block_row0 + rowbase + r;
        if (grow < N) {
            float dn = dinv[grow];
            ushort4 o;
            o.x = f2bf(acc[r][0] * dn);
            o.y = f2bf(acc[r][1] * dn);
            o.z = f2bf(acc[r][2] * dn);
            o.w = f2bf(acc[r][3] * dn);
            *reinterpret_cast<ushort4*>(&Hb[(size_t)grow * DOUT + colbase]) = o;
        }
    }
}

// ---------------- CSR pull aggregation (bf16 pre-scaled operand) ----------------
// out[n] = dinv[n]*( sum_{s in in(n)} h'[s] + h'[n] ) + bias, optional relu.
// Invalid tail lanes gather the zero pad row (index N) -> branch-free inner loop.

__global__ __launch_bounds__(256) void agg1_kernel(const unsigned int* __restrict__ Hb,  // (N+1) x 64 uints
                                                   const int* __restrict__ rowstart,
                                                   const int* __restrict__ csr_src,
                                                   const float* __restrict__ dinv,
                                                   const float* __restrict__ bias,
                                                   float* __restrict__ out, int N) {
    const int wid = (blockIdx.x * 256 + threadIdx.x) >> 6;
    const int lane = threadIdx.x & 63;
    if (wid >= N) return;
    const int e0 = rowstart[wid], e1 = rowstart[wid + 1];

    float accx = 0.f, accy = 0.f;
    for (int eb = e0; eb < e1; eb += 64) {
        int myE = eb + lane;
        int s_l = (myE < e1) ? csr_src[myE] : N;   // N = zero row
        int nbatch = min(64, e1 - eb);
        for (int i = 0; i < nbatch; i += 8) {
            int s[8]; unsigned int u[8];
#pragma unroll
            for (int j = 0; j < 8; ++j) s[j] = __shfl(s_l, i + j);
#pragma unroll
            for (int j = 0; j < 8; ++j) u[j] = Hb[(size_t)s[j] * 64 + lane];
#pragma unroll
            for (int j = 0; j < 8; ++j) {
                accx += bf_lo(u[j]);
                accy += bf_hi(u[j]);
            }
        }
    }
    unsigned int us = Hb[(size_t)wid * 64 + lane];  // self loop
    accx += bf_lo(us);
    accy += bf_hi(us);
    const float dn = dinv[wid];
    accx = fmaf(accx, dn, bias[lane * 2 + 0]);
    accy = fmaf(accy, dn, bias[lane * 2 + 1]);
    accx = fmaxf(accx, 0.f);  // relu (layer 1 only)
    accy = fmaxf(accy, 0.f);
    reinterpret_cast<float2*>(out)[(size_t)wid * 64 + lane] = make_float2(accx, accy);
}

__global__ __launch_bounds__(256) void agg2_kernel(const unsigned short* __restrict__ Hb,  // (N+1) x 64 bf16
                                                   const int* __restrict__ rowstart,
                                                   const int* __restrict__ csr_src,
                                                   const float* __restrict__ dinv,
                                                   const float* __restrict__ bias,
                                                   float* __restrict__ out, int N) {
    const int wid = (blockIdx.x * 256 + threadIdx.x) >> 6;
    const int lane = threadIdx.x & 63;
    if (wid >= N) return;
    const int e0 = rowstart[wid], e1 = rowstart[wid + 1];

    float acc = 0.f;
    for (int eb = e0; eb < e1; eb += 64) {
        int myE = eb + lane;
        int s_l = (myE < e1) ? csr_src[myE] : N;
        int nbatch = min(64, e1 - eb);
        for (int i = 0; i < nbatch; i += 8) {
            int s[8]; unsigned short h[8];
#pragma unroll
            for (int j = 0; j < 8; ++j) s[j] = __shfl(s_l, i + j);
#pragma unroll
            for (int j = 0; j < 8; ++j) h[j] = Hb[(size_t)s[j] * 64 + lane];
#pragma unroll
            for (int j = 0; j < 8; ++j)
                acc += __uint_as_float((unsigned int)h[j] << 16);
        }
    }
    acc += __uint_as_float((unsigned int)Hb[(size_t)wid * 64 + lane] << 16);
    acc = fmaf(acc, dinv[wid], bias[lane]);
    out[(size_t)wid * 64 + lane] = acc;
}

// ---------------- launch ----------------

extern "C" void kernel_launch(void* const* d_in, const int* in_sizes, int n_in,
                              void* d_out, int out_size, void* d_ws, size_t ws_size,
                              hipStream_t stream) {
    const float* x  = (const float*)d_in[0];
    const int*   ei = (const int*)d_in[1];
    const float* W1 = (const float*)d_in[2];
    const float* b1 = (const float*)d_in[3];
    const float* W2 = (const float*)d_in[4];
    const float* b2 = (const float*)d_in[5];
    float* out = (float*)d_out;

    const int N = in_sizes[0] / D_IN;
    const int E = in_sizes[1] / 2;
    const int* src = ei;
    const int* dst = ei + E;

    char* w = (char*)d_ws;
    auto alloc = [&](size_t bytes) {
        char* p = w;
        w += (bytes + 255) & ~(size_t)255;
        return p;
    };
    int*   cnt       = (int*)alloc((size_t)N * 4);
    int*   rowstart  = (int*)alloc((size_t)(N + 1) * 4);
    int*   cursor    = (int*)alloc((size_t)N * 4);
    int*   blockSums = (int*)alloc(256 * 4);
    float* dinv      = (float*)alloc((size_t)N * 4);
    int*   csr       = (int*)alloc((size_t)E * 4);
    unsigned short* h1b = (unsigned short*)alloc((size_t)(N + 1) * D_HID * 2);
    unsigned short* h2b = (unsigned short*)alloc((size_t)(N + 1) * D_OUT * 2);
    float* hg        = (float*)alloc((size_t)N * D_HID * 4);

    const int nb = (N + 1023) / 1024;

    k_zero_int<<<(N + 255) / 256, 256, 0, stream>>>(cnt, N);
    k_count<<<(E + 255) / 256, 256, 0, stream>>>(dst, cnt, E);
    k_dinv<<<(N + 255) / 256, 256, 0, stream>>>(cnt, dinv, N);
    k_scan1<<<nb, 256, 0, stream>>>(cnt, rowstart, blockSums, N);
    k_scan2<<<1, 256, 0, stream>>>(blockSums, nb);
    k_scan3<<<(N + 255) / 256, 256, 0, stream>>>(rowstart, cursor, blockSums, N, E);
    k_fill<<<(E + 255) / 256, 256, 0, stream>>>(src, dst, cursor, csr, E);
    k_zero_pad<<<1, 128, 0, stream>>>(h1b, h2b, N);

    gemm_kernel<D_HID><<<(N + 63) / 64, 256, 0, stream>>>(x, W1, dinv, h1b, N);
    agg1_kernel<<<(N + 3) / 4, 256, 0, stream>>>((const unsigned int*)h1b, rowstart, csr,
                                                 dinv, b1, hg, N);
    gemm_kernel<D_OUT><<<(N + 63) / 64, 256, 0, stream>>>(hg, W2, dinv, h2b, N);
    agg2_kernel<<<(N + 3) / 4, 256, 0, stream>>>(h2b, rowstart, csr, dinv, b2, out, N);
}

// Round 4
// 252.613 us; speedup vs baseline: 2.1556x; 1.5342x over previous
//
#include <hip/hip_runtime.h>

// GCN 2-layer: out = S·relu(S·(X·W1)+b1)·W2 + b2, S = sym-norm adj + self loops.
// N=100000 nodes, E=1600000 edges, D: 128 -> 128 -> 64.
// Aggregation operand stored bf16 pre-scaled by dinv[src]; accumulate fp32.
// CSR built via bucketed counting sort (dst>>9) so all scatter is XCD-local.

#define D_IN  128
#define D_HID 128
#define D_OUT 64
#define NBSHIFT 9           // 512 nodes per bucket; NB = ceil(N/512) <= 256

__device__ __forceinline__ unsigned short f2bf(float f) {
    unsigned int u = __float_as_uint(f);
    u += 0x7fffu + ((u >> 16) & 1u);   // RNE
    return (unsigned short)(u >> 16);
}
__device__ __forceinline__ float bf_lo(unsigned int u) { return __uint_as_float(u << 16); }
__device__ __forceinline__ float bf_hi(unsigned int u) { return __uint_as_float(u & 0xffff0000u); }

// ---------------- graph prep ----------------

__global__ __launch_bounds__(256) void k_zero_int(int* __restrict__ p, int n) {
    int i = blockIdx.x * 256 + threadIdx.x;
    if (i < n) p[i] = 0;
}

// bucket histogram: 8192 edges/block, LDS-reduced, one global add per (block,bucket)
__global__ __launch_bounds__(256) void k_bhist(const int* __restrict__ dst,
                                               int* __restrict__ bcnt, int E, int NB) {
    __shared__ int h[256];
    const int t = threadIdx.x;
    h[t] = 0;
    __syncthreads();
    const int base = blockIdx.x * 8192;
#pragma unroll
    for (int k = 0; k < 32; ++k) {
        int e = base + k * 256 + t;
        if (e < E) atomicAdd(&h[dst[e] >> NBSHIFT], 1);
    }
    __syncthreads();
    if (t < NB && h[t]) atomicAdd(&bcnt[t], h[t]);
}

// exclusive scan of bucket counts (NB <= 256), bases + cursors
__global__ __launch_bounds__(256) void k_bscan(const int* __restrict__ bcnt,
                                               int* __restrict__ bbase,
                                               int* __restrict__ bcur, int NB, int E) {
    __shared__ int ls[256];
    const int t = threadIdx.x;
    int v = (t < NB) ? bcnt[t] : 0;
    ls[t] = v;
    __syncthreads();
    for (int off = 1; off < 256; off <<= 1) {
        int y = (t >= off) ? ls[t - off] : 0;
        __syncthreads();
        ls[t] += y;
        __syncthreads();
    }
    if (t < NB) {
        bbase[t] = ls[t] - v;
        bcur[t]  = ls[t] - v;
    }
    if (t == 0) bbase[NB] = E;
}

// bin edges by bucket into ebuf (bucket-grouped, pairs kept in registers)
__global__ __launch_bounds__(256) void k_bin(const int* __restrict__ src,
                                             const int* __restrict__ dst,
                                             int2* __restrict__ ebuf,
                                             int* __restrict__ bcur, int E, int NB) {
    __shared__ int h[256];
    __shared__ int basep[256];
    const int t = threadIdx.x;
    h[t] = 0;
    __syncthreads();
    const int base = blockIdx.x * 4096;
    int s[16], d[16];
#pragma unroll
    for (int k = 0; k < 16; ++k) {
        int e = base + k * 256 + t;
        bool v = e < E;
        s[k] = v ? src[e] : 0;
        d[k] = v ? dst[e] : -1;
        if (v) atomicAdd(&h[d[k] >> NBSHIFT], 1);
    }
    __syncthreads();
    if (t < NB && h[t]) basep[t] = atomicAdd(&bcur[t], h[t]);
    __syncthreads();
    h[t] = 0;
    __syncthreads();
#pragma unroll
    for (int k = 0; k < 16; ++k) {
        if (d[k] >= 0) {
            int b = d[k] >> NBSHIFT;
            int r = atomicAdd(&h[b], 1);
            ebuf[basep[b] + r] = make_int2(s[k], d[k]);
        }
    }
}

// per-bucket: degree count + local scan -> rowstart, dinv, then csr fill via
// LDS cursors. All scatter stays inside the bucket's contiguous csr segment.
__global__ __launch_bounds__(256) void k_bfill(const int2* __restrict__ ebuf,
                                               const int* __restrict__ bbase,
                                               int* __restrict__ csr,
                                               int* __restrict__ rowstart,
                                               float* __restrict__ dinv,
                                               int N, int NB, int E) {
    __shared__ int cnt[512];
    __shared__ int pref[512];
    __shared__ int tsum[256];
    const int t = threadIdx.x;
    const int b = blockIdx.x;
    const int nb0 = b << NBSHIFT;
    const int NN = min(512, N - nb0);
    const int e0 = bbase[b], e1 = bbase[b + 1];

    cnt[t] = 0;
    cnt[t + 256] = 0;
    __syncthreads();
    for (int e = e0 + t; e < e1; e += 256)
        atomicAdd(&cnt[ebuf[e].y - nb0], 1);
    __syncthreads();

    int a0 = cnt[2 * t], a1 = cnt[2 * t + 1];
    tsum[t] = a0 + a1;
    __syncthreads();
    for (int off = 1; off < 256; off <<= 1) {
        int y = (t >= off) ? tsum[t - off] : 0;
        __syncthreads();
        tsum[t] += y;
        __syncthreads();
    }
    int excl = tsum[t] - (a0 + a1);
    pref[2 * t] = excl;
    pref[2 * t + 1] = excl + a0;
    __syncthreads();

    for (int nl = t; nl < NN; nl += 256) {
        rowstart[nb0 + nl] = e0 + pref[nl];
        dinv[nb0 + nl] = rsqrtf((float)(cnt[nl] + 1));  // +1 self loop
    }
    if (b == NB - 1 && t == 0) rowstart[N] = E;
    __syncthreads();  // rowstart reads of pref done before cursor mutation

    for (int e = e0 + t; e < e1; e += 256) {
        int2 ed = ebuf[e];
        int r = atomicAdd(&pref[ed.y - nb0], 1);
        csr[e0 + r] = ed.x;
    }
}

// zero the pad row (index N) of both bf16 feature buffers
__global__ void k_zero_pad(unsigned short* __restrict__ h1b,
                           unsigned short* __restrict__ h2b, int N) {
    int t = threadIdx.x;
    if (t < 128) h1b[(size_t)N * 128 + t] = 0;
    if (t < 64)  h2b[(size_t)N * 64 + t] = 0;
}

// -------- fp32 GEMM: Hb[n,:] = bf16( (X[n,:]@W) * dinv[n] ), X:[N,128] --------

template <int DOUT>
__global__ __launch_bounds__(256) void gemm_kernel(const float* __restrict__ X,
                                                   const float* __restrict__ W,
                                                   const float* __restrict__ dinv,
                                                   unsigned short* __restrict__ Hb,
                                                   int N) {
    constexpr int K = 128;
    constexpr int TR = 64;
    constexpr int KC = 32;
    constexpr int CPT = 4;
    constexpr int CG = DOUT / CPT;      // 32 or 16
    constexpr int TROWS = 256 / CG;     // 8 or 16
    constexpr int RPT = TR / TROWS;     // 8 or 4
    constexpr int XP = KC + 4;

    __shared__ float Ws[KC][DOUT];
    __shared__ float Xs[TR][XP];

    const int t = threadIdx.x;
    const int cg = t % CG;
    const int tr = t / CG;
    const int colbase = cg * CPT;
    const int rowbase = tr * RPT;
    const int block_row0 = blockIdx.x * TR;

    float acc[RPT][CPT];
#pragma unroll
    for (int r = 0; r < RPT; ++r)
#pragma unroll
        for (int c = 0; c < CPT; ++c) acc[r][c] = 0.f;

    for (int k0 = 0; k0 < K; k0 += KC) {
        __syncthreads();
        for (int i = t * 4; i < KC * DOUT; i += 256 * 4) {
            int kk = i / DOUT, c = i % DOUT;
            *reinterpret_cast<float4*>(&Ws[kk][c]) =
                *reinterpret_cast<const float4*>(&W[(size_t)(k0 + kk) * DOUT + c]);
        }
        for (int i = t; i < TR * (KC / 4); i += 256) {
            int r = i / (KC / 4), c4 = (i % (KC / 4)) * 4;
            int grow = block_row0 + r;
            float4 v = make_float4(0.f, 0.f, 0.f, 0.f);
            if (grow < N)
                v = *reinterpret_cast<const float4*>(&X[(size_t)grow * K + k0 + c4]);
            *reinterpret_cast<float4*>(&Xs[r][c4]) = v;
        }
        __syncthreads();
#pragma unroll
        for (int kk = 0; kk < KC; kk += 4) {
            float4 wv[4];
#pragma unroll
            for (int q = 0; q < 4; ++q)
                wv[q] = *reinterpret_cast<const float4*>(&Ws[kk + q][colbase]);
#pragma unroll
            for (int r = 0; r < RPT; ++r) {
                float4 xv = *reinterpret_cast<const float4*>(&Xs[rowbase + r][kk]);
                acc[r][0] = fmaf(xv.x, wv[0].x, acc[r][0]);
                acc[r][1] = fmaf(xv.x, wv[0].y, acc[r][1]);
                acc[r][2] = fmaf(xv.x, wv[0].z, acc[r][2]);
                acc[r][3] = fmaf(xv.x, wv[0].w, acc[r][3]);
                acc[r][0] = fmaf(xv.y, wv[1].x, acc[r][0]);
                acc[r][1] = fmaf(xv.y, wv[1].y, acc[r][1]);
                acc[r][2] = fmaf(xv.y, wv[1].z, acc[r][2]);
                acc[r][3] = fmaf(xv.y, wv[1].w, acc[r][3]);
                acc[r][0] = fmaf(xv.z, wv[2].x, acc[r][0]);
                acc[r][1] = fmaf(xv.z, wv[2].y, acc[r][1]);
                acc[r][2] = fmaf(xv.z, wv[2].z, acc[r][2]);
                acc[r][3] = fmaf(xv.z, wv[2].w, acc[r][3]);
                acc[r][0] = fmaf(xv.w, wv[3].x, acc[r][0]);
                acc[r][1] = fmaf(xv.w, wv[3].y, acc[r][1]);
                acc[r][2] = fmaf(xv.w, wv[3].z, acc[r][2]);
                acc[r][3] = fmaf(xv.w, wv[3].w, acc[r][3]);
            }
        }
    }

#pragma unroll
    for (int r = 0; r < RPT; ++r) {
        int grow = block_row0 + rowbase + r;
        if (grow < N) {
            float dn = dinv[grow];
            ushort4 o;
            o.x = f2bf(acc[r][0] * dn);
            o.y = f2bf(acc[r][1] * dn);
            o.z = f2bf(acc[r][2] * dn);
            o.w = f2bf(acc[r][3] * dn);
            *reinterpret_cast<ushort4*>(&Hb[(size_t)grow * DOUT + colbase]) = o;
        }
    }
}

// ---------------- CSR pull aggregation (bf16 pre-scaled operand) ----------------

__global__ __launch_bounds__(256) void agg1_kernel(const unsigned int* __restrict__ Hb,  // (N+1) x 64 uints
                                                   const int* __restrict__ rowstart,
                                                   const int* __restrict__ csr_src,
                                                   const float* __restrict__ dinv,
                                                   const float* __restrict__ bias,
                                                   float* __restrict__ out, int N) {
    const int wid = (blockIdx.x * 256 + threadIdx.x) >> 6;
    const int lane = threadIdx.x & 63;
    if (wid >= N) return;
    const int e0 = rowstart[wid], e1 = rowstart[wid + 1];

    float accx = 0.f, accy = 0.f;
    for (int eb = e0; eb < e1; eb += 64) {
        int myE = eb + lane;
        int s_l = (myE < e1) ? csr_src[myE] : N;   // N = zero row
        int nbatch = min(64, e1 - eb);
        for (int i = 0; i < nbatch; i += 8) {
            int s[8]; unsigned int u[8];
#pragma unroll
            for (int j = 0; j < 8; ++j) s[j] = __shfl(s_l, i + j);
#pragma unroll
            for (int j = 0; j < 8; ++j) u[j] = Hb[(size_t)s[j] * 64 + lane];
#pragma unroll
            for (int j = 0; j < 8; ++j) {
                accx += bf_lo(u[j]);
                accy += bf_hi(u[j]);
            }
        }
    }
    unsigned int us = Hb[(size_t)wid * 64 + lane];  // self loop
    accx += bf_lo(us);
    accy += bf_hi(us);
    const float dn = dinv[wid];
    accx = fmaf(accx, dn, bias[lane * 2 + 0]);
    accy = fmaf(accy, dn, bias[lane * 2 + 1]);
    accx = fmaxf(accx, 0.f);  // relu (layer 1 only)
    accy = fmaxf(accy, 0.f);
    reinterpret_cast<float2*>(out)[(size_t)wid * 64 + lane] = make_float2(accx, accy);
}

__global__ __launch_bounds__(256) void agg2_kernel(const unsigned short* __restrict__ Hb,  // (N+1) x 64 bf16
                                                   const int* __restrict__ rowstart,
                                                   const int* __restrict__ csr_src,
                                                   const float* __restrict__ dinv,
                                                   const float* __restrict__ bias,
                                                   float* __restrict__ out, int N) {
    const int wid = (blockIdx.x * 256 + threadIdx.x) >> 6;
    const int lane = threadIdx.x & 63;
    if (wid >= N) return;
    const int e0 = rowstart[wid], e1 = rowstart[wid + 1];

    float acc = 0.f;
    for (int eb = e0; eb < e1; eb += 64) {
        int myE = eb + lane;
        int s_l = (myE < e1) ? csr_src[myE] : N;
        int nbatch = min(64, e1 - eb);
        for (int i = 0; i < nbatch; i += 8) {
            int s[8]; unsigned short h[8];
#pragma unroll
            for (int j = 0; j < 8; ++j) s[j] = __shfl(s_l, i + j);
#pragma unroll
            for (int j = 0; j < 8; ++j) h[j] = Hb[(size_t)s[j] * 64 + lane];
#pragma unroll
            for (int j = 0; j < 8; ++j)
                acc += __uint_as_float((unsigned int)h[j] << 16);
        }
    }
    acc += __uint_as_float((unsigned int)Hb[(size_t)wid * 64 + lane] << 16);
    acc = fmaf(acc, dinv[wid], bias[lane]);
    out[(size_t)wid * 64 + lane] = acc;
}

// ---------------- launch ----------------

extern "C" void kernel_launch(void* const* d_in, const int* in_sizes, int n_in,
                              void* d_out, int out_size, void* d_ws, size_t ws_size,
                              hipStream_t stream) {
    const float* x  = (const float*)d_in[0];
    const int*   ei = (const int*)d_in[1];
    const float* W1 = (const float*)d_in[2];
    const float* b1 = (const float*)d_in[3];
    const float* W2 = (const float*)d_in[4];
    const float* b2 = (const float*)d_in[5];
    float* out = (float*)d_out;

    const int N = in_sizes[0] / D_IN;
    const int E = in_sizes[1] / 2;
    const int* src = ei;
    const int* dst = ei + E;
    const int NB = (N + 511) >> NBSHIFT;   // <= 256

    char* w = (char*)d_ws;
    auto alloc = [&](size_t bytes) {
        char* p = w;
        w += (bytes + 255) & ~(size_t)255;
        return p;
    };
    int*   rowstart  = (int*)alloc((size_t)(N + 1) * 4);
    float* dinv      = (float*)alloc((size_t)N * 4);
    int*   csr       = (int*)alloc((size_t)E * 4);
    unsigned short* h1b = (unsigned short*)alloc((size_t)(N + 1) * D_HID * 2);
    unsigned short* h2b = (unsigned short*)alloc((size_t)(N + 1) * D_OUT * 2);
    float* hg        = (float*)alloc((size_t)N * D_HID * 4);   // also ebuf (E*8 <= N*512)
    int*   bcnt      = (int*)alloc((size_t)NB * 4);
    int*   bbase     = (int*)alloc((size_t)(NB + 1) * 4);
    int*   bcur      = (int*)alloc((size_t)NB * 4);
    int2*  ebuf      = (int2*)hg;   // dead before agg1 writes hg

    k_zero_int<<<1, 256, 0, stream>>>(bcnt, NB);
    k_bhist<<<(E + 8191) / 8192, 256, 0, stream>>>(dst, bcnt, E, NB);
    k_bscan<<<1, 256, 0, stream>>>(bcnt, bbase, bcur, NB, E);
    k_bin<<<(E + 4095) / 4096, 256, 0, stream>>>(src, dst, ebuf, bcur, E, NB);
    k_bfill<<<NB, 256, 0, stream>>>(ebuf, bbase, csr, rowstart, dinv, N, NB, E);
    k_zero_pad<<<1, 128, 0, stream>>>(h1b, h2b, N);

    gemm_kernel<D_HID><<<(N + 63) / 64, 256, 0, stream>>>(x, W1, dinv, h1b, N);
    agg1_kernel<<<(N + 3) / 4, 256, 0, stream>>>((const unsigned int*)h1b, rowstart, csr,
                                                 dinv, b1, hg, N);
    gemm_kernel<D_OUT><<<(N + 63) / 64, 256, 0, stream>>>(hg, W2, dinv, h2b, N);
    agg2_kernel<<<(N + 3) / 4, 256, 0, stream>>>(h2b, rowstart, csr, dinv, b2, out, N);
}

// Round 5
// 221.472 us; speedup vs baseline: 2.4586x; 1.1406x over previous
//
#include <hip/hip_runtime.h>

// GCN 2-layer: out = S·relu(S·(X·W1)+b1)·W2 + b2, S = sym-norm adj + self loops.
// N=100000 nodes, E=1600000 edges, D: 128 -> 128 -> 64.
// GEMMs: MFMA bf16 hi/lo split (3-pass, fp32-accurate). Aggregation operand
// stored bf16 pre-scaled by dinv[src]; accumulate fp32.
// CSR built via bucketed counting sort (dst>>9) so all scatter is XCD-local.

#define D_IN  128
#define D_HID 128
#define D_OUT 64
#define NBSHIFT 9           // 512 nodes per bucket; NB = ceil(N/512) <= 256

typedef short short8 __attribute__((ext_vector_type(8)));
typedef float floatx4 __attribute__((ext_vector_type(4)));

__device__ __forceinline__ unsigned short f2bf(float f) {
    unsigned int u = __float_as_uint(f);
    u += 0x7fffu + ((u >> 16) & 1u);   // RNE
    return (unsigned short)(u >> 16);
}
__device__ __forceinline__ float bf2f(unsigned short h) {
    return __uint_as_float((unsigned int)h << 16);
}
__device__ __forceinline__ float bf_lo(unsigned int u) { return __uint_as_float(u << 16); }
__device__ __forceinline__ float bf_hi(unsigned int u) { return __uint_as_float(u & 0xffff0000u); }

// ---------------- graph prep ----------------

__global__ __launch_bounds__(256) void k_zero_int(int* __restrict__ p, int n) {
    int i = blockIdx.x * 256 + threadIdx.x;
    if (i < n) p[i] = 0;
}

// bucket histogram: 8192 edges/block, LDS-reduced, one global add per (block,bucket)
__global__ __launch_bounds__(256) void k_bhist(const int* __restrict__ dst,
                                               int* __restrict__ bcnt, int E, int NB) {
    __shared__ int h[256];
    const int t = threadIdx.x;
    h[t] = 0;
    __syncthreads();
    const int base = blockIdx.x * 8192;
#pragma unroll
    for (int k = 0; k < 32; ++k) {
        int e = base + k * 256 + t;
        if (e < E) atomicAdd(&h[dst[e] >> NBSHIFT], 1);
    }
    __syncthreads();
    if (t < NB && h[t]) atomicAdd(&bcnt[t], h[t]);
}

// exclusive scan of bucket counts (NB <= 256), bases + cursors
__global__ __launch_bounds__(256) void k_bscan(const int* __restrict__ bcnt,
                                               int* __restrict__ bbase,
                                               int* __restrict__ bcur, int NB, int E) {
    __shared__ int ls[256];
    const int t = threadIdx.x;
    int v = (t < NB) ? bcnt[t] : 0;
    ls[t] = v;
    __syncthreads();
    for (int off = 1; off < 256; off <<= 1) {
        int y = (t >= off) ? ls[t - off] : 0;
        __syncthreads();
        ls[t] += y;
        __syncthreads();
    }
    if (t < NB) {
        bbase[t] = ls[t] - v;
        bcur[t]  = ls[t] - v;
    }
    if (t == 0) bbase[NB] = E;
}

// bin edges by bucket into ebuf (bucket-grouped, pairs kept in registers)
__global__ __launch_bounds__(256) void k_bin(const int* __restrict__ src,
                                             const int* __restrict__ dst,
                                             int2* __restrict__ ebuf,
                                             int* __restrict__ bcur, int E, int NB) {
    __shared__ int h[256];
    __shared__ int basep[256];
    const int t = threadIdx.x;
    h[t] = 0;
    __syncthreads();
    const int base = blockIdx.x * 4096;
    int s[16], d[16];
#pragma unroll
    for (int k = 0; k < 16; ++k) {
        int e = base + k * 256 + t;
        bool v = e < E;
        s[k] = v ? src[e] : 0;
        d[k] = v ? dst[e] : -1;
        if (v) atomicAdd(&h[d[k] >> NBSHIFT], 1);
    }
    __syncthreads();
    if (t < NB && h[t]) basep[t] = atomicAdd(&bcur[t], h[t]);
    __syncthreads();
    h[t] = 0;
    __syncthreads();
#pragma unroll
    for (int k = 0; k < 16; ++k) {
        if (d[k] >= 0) {
            int b = d[k] >> NBSHIFT;
            int r = atomicAdd(&h[b], 1);
            ebuf[basep[b] + r] = make_int2(s[k], d[k]);
        }
    }
}

// per-bucket: degree count + local scan -> rowstart, dinv, then csr fill via
// LDS cursors. All scatter stays inside the bucket's contiguous csr segment.
__global__ __launch_bounds__(256) void k_bfill(const int2* __restrict__ ebuf,
                                               const int* __restrict__ bbase,
                                               int* __restrict__ csr,
                                               int* __restrict__ rowstart,
                                               float* __restrict__ dinv,
                                               int N, int NB, int E) {
    __shared__ int cnt[512];
    __shared__ int pref[512];
    __shared__ int tsum[256];
    const int t = threadIdx.x;
    const int b = blockIdx.x;
    const int nb0 = b << NBSHIFT;
    const int NN = min(512, N - nb0);
    const int e0 = bbase[b], e1 = bbase[b + 1];

    cnt[t] = 0;
    cnt[t + 256] = 0;
    __syncthreads();
    for (int e = e0 + t; e < e1; e += 256)
        atomicAdd(&cnt[ebuf[e].y - nb0], 1);
    __syncthreads();

    int a0 = cnt[2 * t], a1 = cnt[2 * t + 1];
    tsum[t] = a0 + a1;
    __syncthreads();
    for (int off = 1; off < 256; off <<= 1) {
        int y = (t >= off) ? tsum[t - off] : 0;
        __syncthreads();
        tsum[t] += y;
        __syncthreads();
    }
    int excl = tsum[t] - (a0 + a1);
    pref[2 * t] = excl;
    pref[2 * t + 1] = excl + a0;
    __syncthreads();

    for (int nl = t; nl < NN; nl += 256) {
        rowstart[nb0 + nl] = e0 + pref[nl];
        dinv[nb0 + nl] = rsqrtf((float)(cnt[nl] + 1));  // +1 self loop
    }
    if (b == NB - 1 && t == 0) rowstart[N] = E;
    __syncthreads();  // rowstart reads of pref done before cursor mutation

    for (int e = e0 + t; e < e1; e += 256) {
        int2 ed = ebuf[e];
        int r = atomicAdd(&pref[ed.y - nb0], 1);
        csr[e0 + r] = ed.x;
    }
}

// zero the pad row (index N) of both bf16 feature buffers
__global__ void k_zero_pad(unsigned short* __restrict__ h1b,
                           unsigned short* __restrict__ h2b, int N) {
    int t = threadIdx.x;
    if (t < 128) h1b[(size_t)N * 128 + t] = 0;
    if (t < 64)  h2b[(size_t)N * 64 + t] = 0;
}

// ---------------- W hi/lo split into MFMA B-fragment order ----------------
// Layout: Ws[half][kt][ct][lane][i], half0=hi, half1=lo.
// frag element (lane,i) <-> k = kt*32 + (lane>>4)*8 + i, n = ct*16 + (lane&15).
// (Any lane->k bijection is valid as long as A uses the same one.)

template <int DOUT_>
__global__ __launch_bounds__(256) void k_wsplit(const float* __restrict__ W,
                                                unsigned short* __restrict__ Ws) {
    constexpr int NCT = DOUT_ / 16;
    constexpr int HALF = 4 * NCT * 64 * 8;
    int id = blockIdx.x * 256 + threadIdx.x;
    if (id >= HALF) return;
    int i = id & 7;
    int lane = (id >> 3) & 63;
    int ctkt = id >> 9;                 // kt*NCT + ct
    int ct = ctkt % NCT, kt = ctkt / NCT;
    int k = kt * 32 + ((lane >> 4) << 3) + i;
    int n = ct * 16 + (lane & 15);
    float v = W[(size_t)k * DOUT_ + n];
    unsigned short h = f2bf(v);
    Ws[id] = h;
    Ws[HALF + id] = f2bf(v - bf2f(h));
}

// -------- MFMA GEMM: Hb[n,:] = bf16( (X[n,:]@W) * dinv[n] ), X:[N,128] fp32 --------
// Block = 256 thr = 4 waves, 64 rows/block (16 rows/wave), full DOUT per wave.
// W (hi+lo, fragment-order) staged once in LDS; A-frags built in-register from
// coalesced X reads, split hi/lo; 3 MFMA per (kstep, ctile): Ah*Bh+Al*Bh+Ah*Bl.

template <int DOUT_>
__global__ __launch_bounds__(256) void mfma_gemm(const float* __restrict__ X,
                                                 const unsigned short* __restrict__ Wsplit,
                                                 const float* __restrict__ dinv,
                                                 unsigned short* __restrict__ Hb,
                                                 int N) {
    constexpr int NCT = DOUT_ / 16;
    constexpr int HALF = 4 * NCT * 64 * 8;      // shorts per half
    __shared__ unsigned short lds[2 * HALF];    // 64 KB (D=128) / 32 KB (D=64)

    const int t = threadIdx.x;
    {
        const int4* s4 = (const int4*)Wsplit;
        int4* d4 = (int4*)lds;
        constexpr int NV = 2 * HALF / 8;        // 16B chunks
        for (int i = t; i < NV; i += 256) d4[i] = s4[i];
    }
    __syncthreads();

    const int wave = t >> 6, lane = t & 63;
    const int grow = blockIdx.x * 64 + wave * 16 + (lane & 15);
    const int rowc = min(grow, N - 1);
    const int kl = (lane >> 4) << 3;

    floatx4 acc[NCT];
#pragma unroll
    for (int c = 0; c < NCT; ++c) acc[c] = (floatx4)0.f;

#pragma unroll
    for (int kt = 0; kt < 4; ++kt) {
        const float* xp = X + (size_t)rowc * 128 + kt * 32 + kl;
        float4 a0 = *(const float4*)xp;
        float4 a1 = *(const float4*)(xp + 4);
        float xs[8] = {a0.x, a0.y, a0.z, a0.w, a1.x, a1.y, a1.z, a1.w};
        short8 ah, al;
#pragma unroll
        for (int i = 0; i < 8; ++i) {
            unsigned short h = f2bf(xs[i]);
            ah[i] = (short)h;
            al[i] = (short)f2bf(xs[i] - bf2f(h));
        }
#pragma unroll
        for (int c = 0; c < NCT; ++c) {
            const int off = ((kt * NCT + c) * 64 + lane) * 8;
            short8 bh = *(const short8*)&lds[off];
            short8 bl = *(const short8*)&lds[HALF + off];
            acc[c] = __builtin_amdgcn_mfma_f32_16x16x32_bf16(ah, bh, acc[c], 0, 0, 0);
            acc[c] = __builtin_amdgcn_mfma_f32_16x16x32_bf16(al, bh, acc[c], 0, 0, 0);
            acc[c] = __builtin_amdgcn_mfma_f32_16x16x32_bf16(ah, bl, acc[c], 0, 0, 0);
        }
    }

    // C/D layout (verified): col = lane&15, row = (lane>>4)*4 + reg
    const int orow = blockIdx.x * 64 + wave * 16 + ((lane >> 4) << 2);
#pragma unroll
    for (int r = 0; r < 4; ++r) {
        int gr = orow + r;
        if (gr < N) {
            float dn = dinv[gr];
#pragma unroll
            for (int c = 0; c < NCT; ++c)
                Hb[(size_t)gr * DOUT_ + c * 16 + (lane & 15)] = f2bf(acc[c][r] * dn);
        }
    }
}

// ---------------- CSR pull aggregation (bf16 pre-scaled operand) ----------------

__global__ __launch_bounds__(256) void agg1_kernel(const unsigned int* __restrict__ Hb,  // (N+1) x 64 uints
                                                   const int* __restrict__ rowstart,
                                                   const int* __restrict__ csr_src,
                                                   const float* __restrict__ dinv,
                                                   const float* __restrict__ bias,
                                                   float* __restrict__ out, int N) {
    const int wid = (blockIdx.x * 256 + threadIdx.x) >> 6;
    const int lane = threadIdx.x & 63;
    if (wid >= N) return;
    const int e0 = rowstart[wid], e1 = rowstart[wid + 1];

    float accx = 0.f, accy = 0.f;
    for (int eb = e0; eb < e1; eb += 64) {
        int myE = eb + lane;
        int s_l = (myE < e1) ? csr_src[myE] : N;   // N = zero row
        int nbatch = min(64, e1 - eb);
        for (int i = 0; i < nbatch; i += 8) {
            int s[8]; unsigned int u[8];
#pragma unroll
            for (int j = 0; j < 8; ++j) s[j] = __shfl(s_l, i + j);
#pragma unroll
            for (int j = 0; j < 8; ++j) u[j] = Hb[(size_t)s[j] * 64 + lane];
#pragma unroll
            for (int j = 0; j < 8; ++j) {
                accx += bf_lo(u[j]);
                accy += bf_hi(u[j]);
            }
        }
    }
    unsigned int us = Hb[(size_t)wid * 64 + lane];  // self loop
    accx += bf_lo(us);
    accy += bf_hi(us);
    const float dn = dinv[wid];
    accx = fmaf(accx, dn, bias[lane * 2 + 0]);
    accy = fmaf(accy, dn, bias[lane * 2 + 1]);
    accx = fmaxf(accx, 0.f);  // relu (layer 1 only)
    accy = fmaxf(accy, 0.f);
    reinterpret_cast<float2*>(out)[(size_t)wid * 64 + lane] = make_float2(accx, accy);
}

__global__ __launch_bounds__(256) void agg2_kernel(const unsigned short* __restrict__ Hb,  // (N+1) x 64 bf16
                                                   const int* __restrict__ rowstart,
                                                   const int* __restrict__ csr_src,
                                                   const float* __restrict__ dinv,
                                                   const float* __restrict__ bias,
                                                   float* __restrict__ out, int N) {
    const int wid = (blockIdx.x * 256 + threadIdx.x) >> 6;
    const int lane = threadIdx.x & 63;
    if (wid >= N) return;
    const int e0 = rowstart[wid], e1 = rowstart[wid + 1];

    float acc = 0.f;
    for (int eb = e0; eb < e1; eb += 64) {
        int myE = eb + lane;
        int s_l = (myE < e1) ? csr_src[myE] : N;
        int nbatch = min(64, e1 - eb);
        for (int i = 0; i < nbatch; i += 8) {
            int s[8]; unsigned short h[8];
#pragma unroll
            for (int j = 0; j < 8; ++j) s[j] = __shfl(s_l, i + j);
#pragma unroll
            for (int j = 0; j < 8; ++j) h[j] = Hb[(size_t)s[j] * 64 + lane];
#pragma unroll
            for (int j = 0; j < 8; ++j)
                acc += __uint_as_float((unsigned int)h[j] << 16);
        }
    }
    acc += __uint_as_float((unsigned int)Hb[(size_t)wid * 64 + lane] << 16);
    acc = fmaf(acc, dinv[wid], bias[lane]);
    out[(size_t)wid * 64 + lane] = acc;
}

// ---------------- launch ----------------

extern "C" void kernel_launch(void* const* d_in, const int* in_sizes, int n_in,
                              void* d_out, int out_size, void* d_ws, size_t ws_size,
                              hipStream_t stream) {
    const float* x  = (const float*)d_in[0];
    const int*   ei = (const int*)d_in[1];
    const float* W1 = (const float*)d_in[2];
    const float* b1 = (const float*)d_in[3];
    const float* W2 = (const float*)d_in[4];
    const float* b2 = (const float*)d_in[5];
    float* out = (float*)d_out;

    const int N = in_sizes[0] / D_IN;
    const int E = in_sizes[1] / 2;
    const int* src = ei;
    const int* dst = ei + E;
    const int NB = (N + 511) >> NBSHIFT;   // <= 256

    char* w = (char*)d_ws;
    auto alloc = [&](size_t bytes) {
        char* p = w;
        w += (bytes + 255) & ~(size_t)255;
        return p;
    };
    int*   rowstart  = (int*)alloc((size_t)(N + 1) * 4);
    float* dinv      = (float*)alloc((size_t)N * 4);
    int*   csr       = (int*)alloc((size_t)E * 4);
    unsigned short* h1b = (unsigned short*)alloc((size_t)(N + 1) * D_HID * 2);
    unsigned short* h2b = (unsigned short*)alloc((size_t)(N + 1) * D_OUT * 2);
    float* hg        = (float*)alloc((size_t)N * D_HID * 4);   // also ebuf (E*8 <= N*512)
    int*   bcnt      = (int*)alloc((size_t)NB * 4);
    int*   bbase     = (int*)alloc((size_t)(NB + 1) * 4);
    int*   bcur      = (int*)alloc((size_t)NB * 4);
    unsigned short* w1s = (unsigned short*)alloc(2 * 4 * (D_HID / 16) * 64 * 8 * 2);
    unsigned short* w2s = (unsigned short*)alloc(2 * 4 * (D_OUT / 16) * 64 * 8 * 2);
    int2*  ebuf      = (int2*)hg;   // dead before agg1 writes hg

    k_zero_int<<<1, 256, 0, stream>>>(bcnt, NB);
    k_bhist<<<(E + 8191) / 8192, 256, 0, stream>>>(dst, bcnt, E, NB);
    k_bscan<<<1, 256, 0, stream>>>(bcnt, bbase, bcur, NB, E);
    k_bin<<<(E + 4095) / 4096, 256, 0, stream>>>(src, dst, ebuf, bcur, E, NB);
    k_bfill<<<NB, 256, 0, stream>>>(ebuf, bbase, csr, rowstart, dinv, N, NB, E);
    k_zero_pad<<<1, 128, 0, stream>>>(h1b, h2b, N);
    k_wsplit<D_HID><<<(4 * (D_HID / 16) * 64 * 8 + 255) / 256, 256, 0, stream>>>(W1, w1s);
    k_wsplit<D_OUT><<<(4 * (D_OUT / 16) * 64 * 8 + 255) / 256, 256, 0, stream>>>(W2, w2s);

    mfma_gemm<D_HID><<<(N + 63) / 64, 256, 0, stream>>>(x, w1s, dinv, h1b, N);
    agg1_kernel<<<(N + 3) / 4, 256, 0, stream>>>((const unsigned int*)h1b, rowstart, csr,
                                                 dinv, b1, hg, N);
    mfma_gemm<D_OUT><<<(N + 63) / 64, 256, 0, stream>>>(hg, w2s, dinv, h2b, N);
    agg2_kernel<<<(N + 3) / 4, 256, 0, stream>>>(h2b, rowstart, csr, dinv, b2, out, N);
}

// Round 6
// 213.699 us; speedup vs baseline: 2.5481x; 1.0364x over previous
//
#include <hip/hip_runtime.h>

// GCN 2-layer: out = S·relu(S·(X·W1)+b1)·W2 + b2, S = sym-norm adj + self loops.
// N=100000 nodes, E=1600000 edges, D: 128 -> 128 -> 64.
// GEMMs: MFMA bf16 hi/lo split (3-pass, fp32-accurate). Aggregation operand
// stored bf16 pre-scaled by dinv[src]; accumulate fp32. Aggregation gathers
// 16B/lane (lane-group per node: 16 lanes for D=128, 8 for D=64).
// CSR built via bucketed counting sort (dst>>9) so all scatter is XCD-local.

#define D_IN  128
#define D_HID 128
#define D_OUT 64
#define NBSHIFT 9           // 512 nodes per bucket; NB = ceil(N/512) <= 256

typedef short short8 __attribute__((ext_vector_type(8)));
typedef float floatx4 __attribute__((ext_vector_type(4)));

__device__ __forceinline__ unsigned short f2bf(float f) {
    unsigned int u = __float_as_uint(f);
    u += 0x7fffu + ((u >> 16) & 1u);   // RNE
    return (unsigned short)(u >> 16);
}
__device__ __forceinline__ float bf2f(unsigned short h) {
    return __uint_as_float((unsigned int)h << 16);
}
__device__ __forceinline__ float bf_lo(unsigned int u) { return __uint_as_float(u << 16); }
__device__ __forceinline__ float bf_hi(unsigned int u) { return __uint_as_float(u & 0xffff0000u); }

// ---------------- graph prep ----------------

__global__ __launch_bounds__(256) void k_zero_int(int* __restrict__ p, int n) {
    int i = blockIdx.x * 256 + threadIdx.x;
    if (i < n) p[i] = 0;
}

// bucket histogram: 8192 edges/block, LDS-reduced, one global add per (block,bucket)
__global__ __launch_bounds__(256) void k_bhist(const int* __restrict__ dst,
                                               int* __restrict__ bcnt, int E, int NB) {
    __shared__ int h[256];
    const int t = threadIdx.x;
    h[t] = 0;
    __syncthreads();
    const int base = blockIdx.x * 8192;
#pragma unroll
    for (int k = 0; k < 32; ++k) {
        int e = base + k * 256 + t;
        if (e < E) atomicAdd(&h[dst[e] >> NBSHIFT], 1);
    }
    __syncthreads();
    if (t < NB && h[t]) atomicAdd(&bcnt[t], h[t]);
}

// exclusive scan of bucket counts (NB <= 256), bases + cursors
__global__ __launch_bounds__(256) void k_bscan(const int* __restrict__ bcnt,
                                               int* __restrict__ bbase,
                                               int* __restrict__ bcur, int NB, int E) {
    __shared__ int ls[256];
    const int t = threadIdx.x;
    int v = (t < NB) ? bcnt[t] : 0;
    ls[t] = v;
    __syncthreads();
    for (int off = 1; off < 256; off <<= 1) {
        int y = (t >= off) ? ls[t - off] : 0;
        __syncthreads();
        ls[t] += y;
        __syncthreads();
    }
    if (t < NB) {
        bbase[t] = ls[t] - v;
        bcur[t]  = ls[t] - v;
    }
    if (t == 0) bbase[NB] = E;
}

// bin edges by bucket into ebuf (bucket-grouped, pairs kept in registers)
__global__ __launch_bounds__(256) void k_bin(const int* __restrict__ src,
                                             const int* __restrict__ dst,
                                             int2* __restrict__ ebuf,
                                             int* __restrict__ bcur, int E, int NB) {
    __shared__ int h[256];
    __shared__ int basep[256];
    const int t = threadIdx.x;
    h[t] = 0;
    __syncthreads();
    const int base = blockIdx.x * 4096;
    int s[16], d[16];
#pragma unroll
    for (int k = 0; k < 16; ++k) {
        int e = base + k * 256 + t;
        bool v = e < E;
        s[k] = v ? src[e] : 0;
        d[k] = v ? dst[e] : -1;
        if (v) atomicAdd(&h[d[k] >> NBSHIFT], 1);
    }
    __syncthreads();
    if (t < NB && h[t]) basep[t] = atomicAdd(&bcur[t], h[t]);
    __syncthreads();
    h[t] = 0;
    __syncthreads();
#pragma unroll
    for (int k = 0; k < 16; ++k) {
        if (d[k] >= 0) {
            int b = d[k] >> NBSHIFT;
            int r = atomicAdd(&h[b], 1);
            ebuf[basep[b] + r] = make_int2(s[k], d[k]);
        }
    }
}

// per-bucket: degree count + local scan -> rowstart, dinv, then csr fill via
// LDS cursors. All scatter stays inside the bucket's contiguous csr segment.
__global__ __launch_bounds__(256) void k_bfill(const int2* __restrict__ ebuf,
                                               const int* __restrict__ bbase,
                                               int* __restrict__ csr,
                                               int* __restrict__ rowstart,
                                               float* __restrict__ dinv,
                                               int N, int NB, int E) {
    __shared__ int cnt[512];
    __shared__ int pref[512];
    __shared__ int tsum[256];
    const int t = threadIdx.x;
    const int b = blockIdx.x;
    const int nb0 = b << NBSHIFT;
    const int NN = min(512, N - nb0);
    const int e0 = bbase[b], e1 = bbase[b + 1];

    cnt[t] = 0;
    cnt[t + 256] = 0;
    __syncthreads();
    for (int e = e0 + t; e < e1; e += 256)
        atomicAdd(&cnt[ebuf[e].y - nb0], 1);
    __syncthreads();

    int a0 = cnt[2 * t], a1 = cnt[2 * t + 1];
    tsum[t] = a0 + a1;
    __syncthreads();
    for (int off = 1; off < 256; off <<= 1) {
        int y = (t >= off) ? tsum[t - off] : 0;
        __syncthreads();
        tsum[t] += y;
        __syncthreads();
    }
    int excl = tsum[t] - (a0 + a1);
    pref[2 * t] = excl;
    pref[2 * t + 1] = excl + a0;
    __syncthreads();

    for (int nl = t; nl < NN; nl += 256) {
        rowstart[nb0 + nl] = e0 + pref[nl];
        dinv[nb0 + nl] = rsqrtf((float)(cnt[nl] + 1));  // +1 self loop
    }
    if (b == NB - 1 && t == 0) rowstart[N] = E;
    __syncthreads();  // rowstart reads of pref done before cursor mutation

    for (int e = e0 + t; e < e1; e += 256) {
        int2 ed = ebuf[e];
        int r = atomicAdd(&pref[ed.y - nb0], 1);
        csr[e0 + r] = ed.x;
    }
}

// zero the pad row (index N) of both bf16 feature buffers
__global__ void k_zero_pad(unsigned short* __restrict__ h1b,
                           unsigned short* __restrict__ h2b, int N) {
    int t = threadIdx.x;
    if (t < 128) h1b[(size_t)N * 128 + t] = 0;
    if (t < 64)  h2b[(size_t)N * 64 + t] = 0;
}

// ---------------- W hi/lo split into MFMA B-fragment order ----------------
// Layout: Ws[half][kt][ct][lane][i], half0=hi, half1=lo.
// frag element (lane,i) <-> k = kt*32 + (lane>>4)*8 + i, n = ct*16 + (lane&15).

template <int DOUT_>
__global__ __launch_bounds__(256) void k_wsplit(const float* __restrict__ W,
                                                unsigned short* __restrict__ Ws) {
    constexpr int NCT = DOUT_ / 16;
    constexpr int HALF = 4 * NCT * 64 * 8;
    int id = blockIdx.x * 256 + threadIdx.x;
    if (id >= HALF) return;
    int i = id & 7;
    int lane = (id >> 3) & 63;
    int ctkt = id >> 9;                 // kt*NCT + ct
    int ct = ctkt % NCT, kt = ctkt / NCT;
    int k = kt * 32 + ((lane >> 4) << 3) + i;
    int n = ct * 16 + (lane & 15);
    float v = W[(size_t)k * DOUT_ + n];
    unsigned short h = f2bf(v);
    Ws[id] = h;
    Ws[HALF + id] = f2bf(v - bf2f(h));
}

// -------- MFMA GEMM: Hb[n,:] = bf16( (X[n,:]@W) * dinv[n] ), X:[N,128] fp32 --------

template <int DOUT_>
__global__ __launch_bounds__(256) void mfma_gemm(const float* __restrict__ X,
                                                 const unsigned short* __restrict__ Wsplit,
                                                 const float* __restrict__ dinv,
                                                 unsigned short* __restrict__ Hb,
                                                 int N) {
    constexpr int NCT = DOUT_ / 16;
    constexpr int HALF = 4 * NCT * 64 * 8;      // shorts per half
    __shared__ unsigned short lds[2 * HALF];    // 64 KB (D=128) / 32 KB (D=64)

    const int t = threadIdx.x;
    {
        const int4* s4 = (const int4*)Wsplit;
        int4* d4 = (int4*)lds;
        constexpr int NV = 2 * HALF / 8;        // 16B chunks
        for (int i = t; i < NV; i += 256) d4[i] = s4[i];
    }
    __syncthreads();

    const int wave = t >> 6, lane = t & 63;
    const int grow = blockIdx.x * 64 + wave * 16 + (lane & 15);
    const int rowc = min(grow, N - 1);
    const int kl = (lane >> 4) << 3;

    floatx4 acc[NCT];
#pragma unroll
    for (int c = 0; c < NCT; ++c) acc[c] = (floatx4)0.f;

#pragma unroll
    for (int kt = 0; kt < 4; ++kt) {
        const float* xp = X + (size_t)rowc * 128 + kt * 32 + kl;
        float4 a0 = *(const float4*)xp;
        float4 a1 = *(const float4*)(xp + 4);
        float xs[8] = {a0.x, a0.y, a0.z, a0.w, a1.x, a1.y, a1.z, a1.w};
        short8 ah, al;
#pragma unroll
        for (int i = 0; i < 8; ++i) {
            unsigned short h = f2bf(xs[i]);
            ah[i] = (short)h;
            al[i] = (short)f2bf(xs[i] - bf2f(h));
        }
#pragma unroll
        for (int c = 0; c < NCT; ++c) {
            const int off = ((kt * NCT + c) * 64 + lane) * 8;
            short8 bh = *(const short8*)&lds[off];
            short8 bl = *(const short8*)&lds[HALF + off];
            acc[c] = __builtin_amdgcn_mfma_f32_16x16x32_bf16(ah, bh, acc[c], 0, 0, 0);
            acc[c] = __builtin_amdgcn_mfma_f32_16x16x32_bf16(al, bh, acc[c], 0, 0, 0);
            acc[c] = __builtin_amdgcn_mfma_f32_16x16x32_bf16(ah, bl, acc[c], 0, 0, 0);
        }
    }

    // C/D layout (verified): col = lane&15, row = (lane>>4)*4 + reg
    const int orow = blockIdx.x * 64 + wave * 16 + ((lane >> 4) << 2);
#pragma unroll
    for (int r = 0; r < 4; ++r) {
        int gr = orow + r;
        if (gr < N) {
            float dn = dinv[gr];
#pragma unroll
            for (int c = 0; c < NCT; ++c)
                Hb[(size_t)gr * DOUT_ + c * 16 + (lane & 15)] = f2bf(acc[c][r] * dn);
        }
    }
}

// ---------------- CSR pull aggregation (bf16 pre-scaled operand) ----------------
// Lane-group per node: G lanes x 16B = one row per gather, 64/G nodes per wave.
// One global_load_dwordx4 instruction fetches 64/G edge-rows = 1KB.
// Groups iterate to the max degree among the wave's nodes; exhausted groups
// gather the zero pad row (index N, L1-resident) -> branch-free inner loop.

__global__ __launch_bounds__(256) void agg1_kernel(const uint4* __restrict__ H4,  // (N+1) x 16 uint4
                                                   const int* __restrict__ rowstart,
                                                   const int* __restrict__ csr_src,
                                                   const float* __restrict__ dinv,
                                                   const float* __restrict__ bias,
                                                   float* __restrict__ out, int N) {
    const int t = threadIdx.x;
    const int wave = t >> 6, lane = t & 63;
    const int g = lane >> 4, gl = lane & 15;          // 4 groups x 16 lanes
    const int n = blockIdx.x * 16 + wave * 4 + g;
    const bool live = n < N;
    const int e0 = live ? rowstart[n] : 0;
    const int e1 = live ? rowstart[n + 1] : 0;
    const int deg = e1 - e0;
    int m = deg;
    m = max(m, __shfl_xor(m, 16));
    m = max(m, __shfl_xor(m, 32));

    float acc[8] = {0.f, 0.f, 0.f, 0.f, 0.f, 0.f, 0.f, 0.f};
    for (int eb = 0; eb < m; eb += 16) {
        int s_l = (eb + gl < deg) ? csr_src[e0 + eb + gl] : N;
        for (int j = 0; j < 16 && eb + j < m; j += 4) {
            int sj[4]; uint4 u[4];
#pragma unroll
            for (int q = 0; q < 4; ++q) sj[q] = __shfl(s_l, (g << 4) | (j + q));
#pragma unroll
            for (int q = 0; q < 4; ++q) u[q] = H4[(size_t)sj[q] * 16 + gl];
#pragma unroll
            for (int q = 0; q < 4; ++q) {
                acc[0] += bf_lo(u[q].x); acc[1] += bf_hi(u[q].x);
                acc[2] += bf_lo(u[q].y); acc[3] += bf_hi(u[q].y);
                acc[4] += bf_lo(u[q].z); acc[5] += bf_hi(u[q].z);
                acc[6] += bf_lo(u[q].w); acc[7] += bf_hi(u[q].w);
            }
        }
    }
    // self loop
    uint4 us = H4[(size_t)(live ? n : N) * 16 + gl];
    acc[0] += bf_lo(us.x); acc[1] += bf_hi(us.x);
    acc[2] += bf_lo(us.y); acc[3] += bf_hi(us.y);
    acc[4] += bf_lo(us.z); acc[5] += bf_hi(us.z);
    acc[6] += bf_lo(us.w); acc[7] += bf_hi(us.w);

    if (live) {
        const float dn = dinv[n];
        float4 o0, o1;
        o0.x = fmaxf(fmaf(acc[0], dn, bias[gl * 8 + 0]), 0.f);
        o0.y = fmaxf(fmaf(acc[1], dn, bias[gl * 8 + 1]), 0.f);
        o0.z = fmaxf(fmaf(acc[2], dn, bias[gl * 8 + 2]), 0.f);
        o0.w = fmaxf(fmaf(acc[3], dn, bias[gl * 8 + 3]), 0.f);
        o1.x = fmaxf(fmaf(acc[4], dn, bias[gl * 8 + 4]), 0.f);
        o1.y = fmaxf(fmaf(acc[5], dn, bias[gl * 8 + 5]), 0.f);
        o1.z = fmaxf(fmaf(acc[6], dn, bias[gl * 8 + 6]), 0.f);
        o1.w = fmaxf(fmaf(acc[7], dn, bias[gl * 8 + 7]), 0.f);
        float* op = out + (size_t)n * 128 + gl * 8;
        *reinterpret_cast<float4*>(op) = o0;
        *reinterpret_cast<float4*>(op + 4) = o1;
    }
}

__global__ __launch_bounds__(256) void agg2_kernel(const uint4* __restrict__ H4,  // (N+1) x 8 uint4
                                                   const int* __restrict__ rowstart,
                                                   const int* __restrict__ csr_src,
                                                   const float* __restrict__ dinv,
                                                   const float* __restrict__ bias,
                                                   float* __restrict__ out, int N) {
    const int t = threadIdx.x;
    const int wave = t >> 6, lane = t & 63;
    const int g = lane >> 3, gl = lane & 7;           // 8 groups x 8 lanes
    const int n = blockIdx.x * 32 + wave * 8 + g;
    const bool live = n < N;
    const int e0 = live ? rowstart[n] : 0;
    const int e1 = live ? rowstart[n + 1] : 0;
    const int deg = e1 - e0;
    int m = deg;
    m = max(m, __shfl_xor(m, 8));
    m = max(m, __shfl_xor(m, 16));
    m = max(m, __shfl_xor(m, 32));

    float acc[8] = {0.f, 0.f, 0.f, 0.f, 0.f, 0.f, 0.f, 0.f};
    for (int eb = 0; eb < m; eb += 8) {
        int s_l = (eb + gl < deg) ? csr_src[e0 + eb + gl] : N;
        for (int j = 0; j < 8 && eb + j < m; j += 4) {
            int sj[4]; uint4 u[4];
#pragma unroll
            for (int q = 0; q < 4; ++q) sj[q] = __shfl(s_l, (g << 3) | (j + q));
#pragma unroll
            for (int q = 0; q < 4; ++q) u[q] = H4[(size_t)sj[q] * 8 + gl];
#pragma unroll
            for (int q = 0; q < 4; ++q) {
                acc[0] += bf_lo(u[q].x); acc[1] += bf_hi(u[q].x);
                acc[2] += bf_lo(u[q].y); acc[3] += bf_hi(u[q].y);
                acc[4] += bf_lo(u[q].z); acc[5] += bf_hi(u[q].z);
                acc[6] += bf_lo(u[q].w); acc[7] += bf_hi(u[q].w);
            }
        }
    }
    uint4 us = H4[(size_t)(live ? n : N) * 8 + gl];
    acc[0] += bf_lo(us.x); acc[1] += bf_hi(us.x);
    acc[2] += bf_lo(us.y); acc[3] += bf_hi(us.y);
    acc[4] += bf_lo(us.z); acc[5] += bf_hi(us.z);
    acc[6] += bf_lo(us.w); acc[7] += bf_hi(us.w);

    if (live) {
        const float dn = dinv[n];
        float4 o0, o1;
        o0.x = fmaf(acc[0], dn, bias[gl * 8 + 0]);
        o0.y = fmaf(acc[1], dn, bias[gl * 8 + 1]);
        o0.z = fmaf(acc[2], dn, bias[gl * 8 + 2]);
        o0.w = fmaf(acc[3], dn, bias[gl * 8 + 3]);
        o1.x = fmaf(acc[4], dn, bias[gl * 8 + 4]);
        o1.y = fmaf(acc[5], dn, bias[gl * 8 + 5]);
        o1.z = fmaf(acc[6], dn, bias[gl * 8 + 6]);
        o1.w = fmaf(acc[7], dn, bias[gl * 8 + 7]);
        float* op = out + (size_t)n * 64 + gl * 8;
        *reinterpret_cast<float4*>(op) = o0;
        *reinterpret_cast<float4*>(op + 4) = o1;
    }
}

// ---------------- launch ----------------

extern "C" void kernel_launch(void* const* d_in, const int* in_sizes, int n_in,
                              void* d_out, int out_size, void* d_ws, size_t ws_size,
                              hipStream_t stream) {
    const float* x  = (const float*)d_in[0];
    const int*   ei = (const int*)d_in[1];
    const float* W1 = (const float*)d_in[2];
    const float* b1 = (const float*)d_in[3];
    const float* W2 = (const float*)d_in[4];
    const float* b2 = (const float*)d_in[5];
    float* out = (float*)d_out;

    const int N = in_sizes[0] / D_IN;
    const int E = in_sizes[1] / 2;
    const int* src = ei;
    const int* dst = ei + E;
    const int NB = (N + 511) >> NBSHIFT;   // <= 256

    char* w = (char*)d_ws;
    auto alloc = [&](size_t bytes) {
        char* p = w;
        w += (bytes + 255) & ~(size_t)255;
        return p;
    };
    int*   rowstart  = (int*)alloc((size_t)(N + 1) * 4);
    float* dinv      = (float*)alloc((size_t)N * 4);
    int*   csr       = (int*)alloc((size_t)E * 4);
    unsigned short* h1b = (unsigned short*)alloc((size_t)(N + 1) * D_HID * 2);
    unsigned short* h2b = (unsigned short*)alloc((size_t)(N + 1) * D_OUT * 2);
    float* hg        = (float*)alloc((size_t)N * D_HID * 4);   // also ebuf (E*8 <= N*512)
    int*   bcnt      = (int*)alloc((size_t)NB * 4);
    int*   bbase     = (int*)alloc((size_t)(NB + 1) * 4);
    int*   bcur      = (int*)alloc((size_t)NB * 4);
    unsigned short* w1s = (unsigned short*)alloc(2 * 4 * (D_HID / 16) * 64 * 8 * 2);
    unsigned short* w2s = (unsigned short*)alloc(2 * 4 * (D_OUT / 16) * 64 * 8 * 2);
    int2*  ebuf      = (int2*)hg;   // dead before agg1 writes hg

    k_zero_int<<<1, 256, 0, stream>>>(bcnt, NB);
    k_bhist<<<(E + 8191) / 8192, 256, 0, stream>>>(dst, bcnt, E, NB);
    k_bscan<<<1, 256, 0, stream>>>(bcnt, bbase, bcur, NB, E);
    k_bin<<<(E + 4095) / 4096, 256, 0, stream>>>(src, dst, ebuf, bcur, E, NB);
    k_bfill<<<NB, 256, 0, stream>>>(ebuf, bbase, csr, rowstart, dinv, N, NB, E);
    k_zero_pad<<<1, 128, 0, stream>>>(h1b, h2b, N);
    k_wsplit<D_HID><<<(4 * (D_HID / 16) * 64 * 8 + 255) / 256, 256, 0, stream>>>(W1, w1s);
    k_wsplit<D_OUT><<<(4 * (D_OUT / 16) * 64 * 8 + 255) / 256, 256, 0, stream>>>(W2, w2s);

    mfma_gemm<D_HID><<<(N + 63) / 64, 256, 0, stream>>>(x, w1s, dinv, h1b, N);
    agg1_kernel<<<(N + 15) / 16, 256, 0, stream>>>((const uint4*)h1b, rowstart, csr,
                                                   dinv, b1, hg, N);
    mfma_gemm<D_OUT><<<(N + 63) / 64, 256, 0, stream>>>(hg, w2s, dinv, h2b, N);
    agg2_kernel<<<(N + 31) / 32, 256, 0, stream>>>((const uint4*)h2b, rowstart, csr,
                                                   dinv, b2, out, N);
}

// Round 7
// 198.005 us; speedup vs baseline: 2.7500x; 1.0793x over previous
//
#include <hip/hip_runtime.h>

// GCN 2-layer: out = S·relu(S·(X·W1)+b1)·W2 + b2, S = sym-norm adj + self loops.
// N=100000 nodes, E=1600000 edges, D: 128 -> 128 -> 64.
// GEMMs: MFMA bf16 hi/lo split (fp32-accurate). Aggregation operand stored
// bf16 pre-scaled by dinv[src]; accumulate fp32. agg1 is column-partitioned
// across XCD halves (per-XCD working set 12.8MB) and writes hg in bf16.
// CSR built via bucketed counting sort (dst>>9) so all scatter is XCD-local.

#define D_IN  128
#define D_HID 128
#define D_OUT 64
#define NBSHIFT 9           // 512 nodes per bucket; NB = ceil(N/512) <= 256

typedef short short8 __attribute__((ext_vector_type(8)));
typedef float floatx4 __attribute__((ext_vector_type(4)));

__device__ __forceinline__ unsigned short f2bf(float f) {
    unsigned int u = __float_as_uint(f);
    u += 0x7fffu + ((u >> 16) & 1u);   // RNE
    return (unsigned short)(u >> 16);
}
__device__ __forceinline__ float bf2f(unsigned short h) {
    return __uint_as_float((unsigned int)h << 16);
}
__device__ __forceinline__ float bf_lo(unsigned int u) { return __uint_as_float(u << 16); }
__device__ __forceinline__ float bf_hi(unsigned int u) { return __uint_as_float(u & 0xffff0000u); }

// ---------------- graph prep ----------------

__global__ __launch_bounds__(256) void k_zero_int(int* __restrict__ p, int n) {
    int i = blockIdx.x * 256 + threadIdx.x;
    if (i < n) p[i] = 0;
}

// bucket histogram: 8192 edges/block, LDS-reduced, one global add per (block,bucket)
__global__ __launch_bounds__(256) void k_bhist(const int* __restrict__ dst,
                                               int* __restrict__ bcnt, int E, int NB) {
    __shared__ int h[256];
    const int t = threadIdx.x;
    h[t] = 0;
    __syncthreads();
    const int base = blockIdx.x * 8192;
#pragma unroll
    for (int k = 0; k < 32; ++k) {
        int e = base + k * 256 + t;
        if (e < E) atomicAdd(&h[dst[e] >> NBSHIFT], 1);
    }
    __syncthreads();
    if (t < NB && h[t]) atomicAdd(&bcnt[t], h[t]);
}

// exclusive scan of bucket counts (NB <= 256), bases + cursors
__global__ __launch_bounds__(256) void k_bscan(const int* __restrict__ bcnt,
                                               int* __restrict__ bbase,
                                               int* __restrict__ bcur, int NB, int E) {
    __shared__ int ls[256];
    const int t = threadIdx.x;
    int v = (t < NB) ? bcnt[t] : 0;
    ls[t] = v;
    __syncthreads();
    for (int off = 1; off < 256; off <<= 1) {
        int y = (t >= off) ? ls[t - off] : 0;
        __syncthreads();
        ls[t] += y;
        __syncthreads();
    }
    if (t < NB) {
        bbase[t] = ls[t] - v;
        bcur[t]  = ls[t] - v;
    }
    if (t == 0) bbase[NB] = E;
}

// bin edges by bucket into ebuf (bucket-grouped, pairs kept in registers)
__global__ __launch_bounds__(256) void k_bin(const int* __restrict__ src,
                                             const int* __restrict__ dst,
                                             int2* __restrict__ ebuf,
                                             int* __restrict__ bcur, int E, int NB) {
    __shared__ int h[256];
    __shared__ int basep[256];
    const int t = threadIdx.x;
    h[t] = 0;
    __syncthreads();
    const int base = blockIdx.x * 4096;
    int s[16], d[16];
#pragma unroll
    for (int k = 0; k < 16; ++k) {
        int e = base + k * 256 + t;
        bool v = e < E;
        s[k] = v ? src[e] : 0;
        d[k] = v ? dst[e] : -1;
        if (v) atomicAdd(&h[d[k] >> NBSHIFT], 1);
    }
    __syncthreads();
    if (t < NB && h[t]) basep[t] = atomicAdd(&bcur[t], h[t]);
    __syncthreads();
    h[t] = 0;
    __syncthreads();
#pragma unroll
    for (int k = 0; k < 16; ++k) {
        if (d[k] >= 0) {
            int b = d[k] >> NBSHIFT;
            int r = atomicAdd(&h[b], 1);
            ebuf[basep[b] + r] = make_int2(s[k], d[k]);
        }
    }
}

// per-bucket: degree count + local scan -> rowstart, dinv, then csr fill via
// LDS cursors. All scatter stays inside the bucket's contiguous csr segment.
__global__ __launch_bounds__(256) void k_bfill(const int2* __restrict__ ebuf,
                                               const int* __restrict__ bbase,
                                               int* __restrict__ csr,
                                               int* __restrict__ rowstart,
                                               float* __restrict__ dinv,
                                               int N, int NB, int E) {
    __shared__ int cnt[512];
    __shared__ int pref[512];
    __shared__ int tsum[256];
    const int t = threadIdx.x;
    const int b = blockIdx.x;
    const int nb0 = b << NBSHIFT;
    const int NN = min(512, N - nb0);
    const int e0 = bbase[b], e1 = bbase[b + 1];

    cnt[t] = 0;
    cnt[t + 256] = 0;
    __syncthreads();
    for (int e = e0 + t; e < e1; e += 256)
        atomicAdd(&cnt[ebuf[e].y - nb0], 1);
    __syncthreads();

    int a0 = cnt[2 * t], a1 = cnt[2 * t + 1];
    tsum[t] = a0 + a1;
    __syncthreads();
    for (int off = 1; off < 256; off <<= 1) {
        int y = (t >= off) ? tsum[t - off] : 0;
        __syncthreads();
        tsum[t] += y;
        __syncthreads();
    }
    int excl = tsum[t] - (a0 + a1);
    pref[2 * t] = excl;
    pref[2 * t + 1] = excl + a0;
    __syncthreads();

    for (int nl = t; nl < NN; nl += 256) {
        rowstart[nb0 + nl] = e0 + pref[nl];
        dinv[nb0 + nl] = rsqrtf((float)(cnt[nl] + 1));  // +1 self loop
    }
    if (b == NB - 1 && t == 0) rowstart[N] = E;
    __syncthreads();  // rowstart reads of pref done before cursor mutation

    for (int e = e0 + t; e < e1; e += 256) {
        int2 ed = ebuf[e];
        int r = atomicAdd(&pref[ed.y - nb0], 1);
        csr[e0 + r] = ed.x;
    }
}

// zero the pad row (index N) of both bf16 feature buffers
__global__ void k_zero_pad(unsigned short* __restrict__ h1b,
                           unsigned short* __restrict__ h2b, int N) {
    int t = threadIdx.x;
    if (t < 128) h1b[(size_t)N * 128 + t] = 0;
    if (t < 64)  h2b[(size_t)N * 64 + t] = 0;
}

// ---------------- W hi/lo split into MFMA B-fragment order ----------------
// Layout: Ws[half][kt][ct][lane][i], half0=hi, half1=lo.
// frag element (lane,i) <-> k = kt*32 + (lane>>4)*8 + i, n = ct*16 + (lane&15).

template <int DOUT_>
__global__ __launch_bounds__(256) void k_wsplit(const float* __restrict__ W,
                                                unsigned short* __restrict__ Ws) {
    constexpr int NCT = DOUT_ / 16;
    constexpr int HALF = 4 * NCT * 64 * 8;
    int id = blockIdx.x * 256 + threadIdx.x;
    if (id >= HALF) return;
    int i = id & 7;
    int lane = (id >> 3) & 63;
    int ctkt = id >> 9;                 // kt*NCT + ct
    int ct = ctkt % NCT, kt = ctkt / NCT;
    int k = kt * 32 + ((lane >> 4) << 3) + i;
    int n = ct * 16 + (lane & 15);
    float v = W[(size_t)k * DOUT_ + n];
    unsigned short h = f2bf(v);
    Ws[id] = h;
    Ws[HALF + id] = f2bf(v - bf2f(h));
}

// -------- MFMA GEMM (fp32 input): Hb = bf16((X@W)*dinv), X:[N,128] fp32 --------

template <int DOUT_>
__global__ __launch_bounds__(256) void mfma_gemm(const float* __restrict__ X,
                                                 const unsigned short* __restrict__ Wsplit,
                                                 const float* __restrict__ dinv,
                                                 unsigned short* __restrict__ Hb,
                                                 int N) {
    constexpr int NCT = DOUT_ / 16;
    constexpr int HALF = 4 * NCT * 64 * 8;      // shorts per half
    __shared__ unsigned short lds[2 * HALF];    // 64 KB (D=128)

    const int t = threadIdx.x;
    {
        const int4* s4 = (const int4*)Wsplit;
        int4* d4 = (int4*)lds;
        constexpr int NV = 2 * HALF / 8;
        for (int i = t; i < NV; i += 256) d4[i] = s4[i];
    }
    __syncthreads();

    const int wave = t >> 6, lane = t & 63;
    const int grow = blockIdx.x * 64 + wave * 16 + (lane & 15);
    const int rowc = min(grow, N - 1);
    const int kl = (lane >> 4) << 3;

    floatx4 acc[NCT];
#pragma unroll
    for (int c = 0; c < NCT; ++c) acc[c] = (floatx4)0.f;

#pragma unroll
    for (int kt = 0; kt < 4; ++kt) {
        const float* xp = X + (size_t)rowc * 128 + kt * 32 + kl;
        float4 a0 = *(const float4*)xp;
        float4 a1 = *(const float4*)(xp + 4);
        float xs[8] = {a0.x, a0.y, a0.z, a0.w, a1.x, a1.y, a1.z, a1.w};
        short8 ah, al;
#pragma unroll
        for (int i = 0; i < 8; ++i) {
            unsigned short h = f2bf(xs[i]);
            ah[i] = (short)h;
            al[i] = (short)f2bf(xs[i] - bf2f(h));
        }
#pragma unroll
        for (int c = 0; c < NCT; ++c) {
            const int off = ((kt * NCT + c) * 64 + lane) * 8;
            short8 bh = *(const short8*)&lds[off];
            short8 bl = *(const short8*)&lds[HALF + off];
            acc[c] = __builtin_amdgcn_mfma_f32_16x16x32_bf16(ah, bh, acc[c], 0, 0, 0);
            acc[c] = __builtin_amdgcn_mfma_f32_16x16x32_bf16(al, bh, acc[c], 0, 0, 0);
            acc[c] = __builtin_amdgcn_mfma_f32_16x16x32_bf16(ah, bl, acc[c], 0, 0, 0);
        }
    }

    // C/D layout (verified): col = lane&15, row = (lane>>4)*4 + reg
    const int orow = blockIdx.x * 64 + wave * 16 + ((lane >> 4) << 2);
#pragma unroll
    for (int r = 0; r < 4; ++r) {
        int gr = orow + r;
        if (gr < N) {
            float dn = dinv[gr];
#pragma unroll
            for (int c = 0; c < NCT; ++c)
                Hb[(size_t)gr * DOUT_ + c * 16 + (lane & 15)] = f2bf(acc[c][r] * dn);
        }
    }
}

// -------- MFMA GEMM (bf16 input): Hb = bf16((Xb@W)*dinv), Xb:[N,128] bf16 --------
// A is already bf16 -> no A-lo pass; keep W hi+lo (2 MFMA per tile).

template <int DOUT_>
__global__ __launch_bounds__(256) void mfma_gemm_b(const unsigned short* __restrict__ Xb,
                                                   const unsigned short* __restrict__ Wsplit,
                                                   const float* __restrict__ dinv,
                                                   unsigned short* __restrict__ Hb,
                                                   int N) {
    constexpr int NCT = DOUT_ / 16;
    constexpr int HALF = 4 * NCT * 64 * 8;
    __shared__ unsigned short lds[2 * HALF];    // 32 KB (D=64)

    const int t = threadIdx.x;
    {
        const int4* s4 = (const int4*)Wsplit;
        int4* d4 = (int4*)lds;
        constexpr int NV = 2 * HALF / 8;
        for (int i = t; i < NV; i += 256) d4[i] = s4[i];
    }
    __syncthreads();

    const int wave = t >> 6, lane = t & 63;
    const int grow = blockIdx.x * 64 + wave * 16 + (lane & 15);
    const int rowc = min(grow, N - 1);
    const int kl = (lane >> 4) << 3;

    floatx4 acc[NCT];
#pragma unroll
    for (int c = 0; c < NCT; ++c) acc[c] = (floatx4)0.f;

#pragma unroll
    for (int kt = 0; kt < 4; ++kt) {
        short8 ah = *(const short8*)(Xb + (size_t)rowc * 128 + kt * 32 + kl);
#pragma unroll
        for (int c = 0; c < NCT; ++c) {
            const int off = ((kt * NCT + c) * 64 + lane) * 8;
            short8 bh = *(const short8*)&lds[off];
            short8 bl = *(const short8*)&lds[HALF + off];
            acc[c] = __builtin_amdgcn_mfma_f32_16x16x32_bf16(ah, bh, acc[c], 0, 0, 0);
            acc[c] = __builtin_amdgcn_mfma_f32_16x16x32_bf16(ah, bl, acc[c], 0, 0, 0);
        }
    }

    const int orow = blockIdx.x * 64 + wave * 16 + ((lane >> 4) << 2);
#pragma unroll
    for (int r = 0; r < 4; ++r) {
        int gr = orow + r;
        if (gr < N) {
            float dn = dinv[gr];
#pragma unroll
            for (int c = 0; c < NCT; ++c)
                Hb[(size_t)gr * DOUT_ + c * 16 + (lane & 15)] = f2bf(acc[c][r] * dn);
        }
    }
}

// ---------------- CSR pull aggregation (bf16 pre-scaled operand) ----------------
// agg1: column-partitioned across XCDs. colhalf = (blockIdx%8)>>2, so XCDs 0-3
// only touch cols [0,64) of H (12.8MB working set) and XCDs 4-7 cols [64,128).
// 8 lanes x 16B = one 128B half-row per node-group, 8 nodes/wave, 32/block.
// Groups iterate to the wave-max degree; exhausted lanes gather the zero pad
// row (index N, cache-resident) -> branch-free inner loop. Output hg in bf16.

__global__ __launch_bounds__(256) void agg1_kernel(const uint4* __restrict__ H4,  // (N+1) x 16 uint4
                                                   const int* __restrict__ rowstart,
                                                   const int* __restrict__ csr_src,
                                                   const float* __restrict__ dinv,
                                                   const float* __restrict__ bias,
                                                   unsigned short* __restrict__ outb,
                                                   int N, int NBK) {
    const int xcd = blockIdx.x & 7;
    const int ch  = xcd >> 2;                       // column half
    const int nb  = (blockIdx.x >> 3) * 4 + (xcd & 3);
    if (nb >= NBK) return;
    const int t = threadIdx.x;
    const int wave = t >> 6, lane = t & 63;
    const int g = lane >> 3, gl = lane & 7;         // 8 groups x 8 lanes
    const int n = nb * 32 + wave * 8 + g;
    const bool live = n < N;
    const int e0 = live ? rowstart[n] : 0;
    const int deg = live ? rowstart[n + 1] - e0 : 0;
    int m = deg;
    m = max(m, __shfl_xor(m, 8));
    m = max(m, __shfl_xor(m, 16));
    m = max(m, __shfl_xor(m, 32));

    const int cb = ch * 8;                          // uint4 offset of column half
    float acc[8] = {0.f, 0.f, 0.f, 0.f, 0.f, 0.f, 0.f, 0.f};
    for (int eb = 0; eb < m; eb += 8) {
        int s_l = (eb + gl < deg) ? csr_src[e0 + eb + gl] : N;  // N = zero row
        int sj[8]; uint4 u[8];
#pragma unroll
        for (int q = 0; q < 8; ++q) sj[q] = __shfl(s_l, (g << 3) | q);
#pragma unroll
        for (int q = 0; q < 8; ++q) u[q] = H4[(size_t)sj[q] * 16 + cb + gl];
#pragma unroll
        for (int q = 0; q < 8; ++q) {
            acc[0] += bf_lo(u[q].x); acc[1] += bf_hi(u[q].x);
            acc[2] += bf_lo(u[q].y); acc[3] += bf_hi(u[q].y);
            acc[4] += bf_lo(u[q].z); acc[5] += bf_hi(u[q].z);
            acc[6] += bf_lo(u[q].w); acc[7] += bf_hi(u[q].w);
        }
    }
    // self loop
    uint4 us = H4[(size_t)(live ? n : N) * 16 + cb + gl];
    acc[0] += bf_lo(us.x); acc[1] += bf_hi(us.x);
    acc[2] += bf_lo(us.y); acc[3] += bf_hi(us.y);
    acc[4] += bf_lo(us.z); acc[5] += bf_hi(us.z);
    acc[6] += bf_lo(us.w); acc[7] += bf_hi(us.w);

    if (live) {
        const float dn = dinv[n];
        const float* bp = bias + ch * 64 + gl * 8;
        unsigned short o[8];
#pragma unroll
        for (int j = 0; j < 8; ++j)
            o[j] = f2bf(fmaxf(fmaf(acc[j], dn, bp[j]), 0.f));  // relu
        *reinterpret_cast<int4*>(&outb[(size_t)n * 128 + ch * 64 + gl * 8]) =
            *reinterpret_cast<const int4*>(o);
    }
}

__global__ __launch_bounds__(256) void agg2_kernel(const uint4* __restrict__ H4,  // (N+1) x 8 uint4
                                                   const int* __restrict__ rowstart,
                                                   const int* __restrict__ csr_src,
                                                   const float* __restrict__ dinv,
                                                   const float* __restrict__ bias,
                                                   float* __restrict__ out, int N) {
    const int t = threadIdx.x;
    const int wave = t >> 6, lane = t & 63;
    const int g = lane >> 3, gl = lane & 7;           // 8 groups x 8 lanes
    const int n = blockIdx.x * 32 + wave * 8 + g;
    const bool live = n < N;
    const int e0 = live ? rowstart[n] : 0;
    const int e1 = live ? rowstart[n + 1] : 0;
    const int deg = e1 - e0;
    int m = deg;
    m = max(m, __shfl_xor(m, 8));
    m = max(m, __shfl_xor(m, 16));
    m = max(m, __shfl_xor(m, 32));

    float acc[8] = {0.f, 0.f, 0.f, 0.f, 0.f, 0.f, 0.f, 0.f};
    for (int eb = 0; eb < m; eb += 8) {
        int s_l = (eb + gl < deg) ? csr_src[e0 + eb + gl] : N;
        int sj[8]; uint4 u[8];
#pragma unroll
        for (int q = 0; q < 8; ++q) sj[q] = __shfl(s_l, (g << 3) | q);
#pragma unroll
        for (int q = 0; q < 8; ++q) u[q] = H4[(size_t)sj[q] * 8 + gl];
#pragma unroll
        for (int q = 0; q < 8; ++q) {
            acc[0] += bf_lo(u[q].x); acc[1] += bf_hi(u[q].x);
            acc[2] += bf_lo(u[q].y); acc[3] += bf_hi(u[q].y);
            acc[4] += bf_lo(u[q].z); acc[5] += bf_hi(u[q].z);
            acc[6] += bf_lo(u[q].w); acc[7] += bf_hi(u[q].w);
        }
    }
    uint4 us = H4[(size_t)(live ? n : N) * 8 + gl];
    acc[0] += bf_lo(us.x); acc[1] += bf_hi(us.x);
    acc[2] += bf_lo(us.y); acc[3] += bf_hi(us.y);
    acc[4] += bf_lo(us.z); acc[5] += bf_hi(us.z);
    acc[6] += bf_lo(us.w); acc[7] += bf_hi(us.w);

    if (live) {
        const float dn = dinv[n];
        float4 o0, o1;
        o0.x = fmaf(acc[0], dn, bias[gl * 8 + 0]);
        o0.y = fmaf(acc[1], dn, bias[gl * 8 + 1]);
        o0.z = fmaf(acc[2], dn, bias[gl * 8 + 2]);
        o0.w = fmaf(acc[3], dn, bias[gl * 8 + 3]);
        o1.x = fmaf(acc[4], dn, bias[gl * 8 + 4]);
        o1.y = fmaf(acc[5], dn, bias[gl * 8 + 5]);
        o1.z = fmaf(acc[6], dn, bias[gl * 8 + 6]);
        o1.w = fmaf(acc[7], dn, bias[gl * 8 + 7]);
        float* op = out + (size_t)n * 64 + gl * 8;
        *reinterpret_cast<float4*>(op) = o0;
        *reinterpret_cast<float4*>(op + 4) = o1;
    }
}

// ---------------- launch ----------------

extern "C" void kernel_launch(void* const* d_in, const int* in_sizes, int n_in,
                              void* d_out, int out_size, void* d_ws, size_t ws_size,
                              hipStream_t stream) {
    const float* x  = (const float*)d_in[0];
    const int*   ei = (const int*)d_in[1];
    const float* W1 = (const float*)d_in[2];
    const float* b1 = (const float*)d_in[3];
    const float* W2 = (const float*)d_in[4];
    const float* b2 = (const float*)d_in[5];
    float* out = (float*)d_out;

    const int N = in_sizes[0] / D_IN;
    const int E = in_sizes[1] / 2;
    const int* src = ei;
    const int* dst = ei + E;
    const int NB = (N + 511) >> NBSHIFT;   // <= 256

    char* w = (char*)d_ws;
    auto alloc = [&](size_t bytes) {
        char* p = w;
        w += (bytes + 255) & ~(size_t)255;
        return p;
    };
    int*   rowstart  = (int*)alloc((size_t)(N + 1) * 4);
    float* dinv      = (float*)alloc((size_t)N * 4);
    int*   csr       = (int*)alloc((size_t)E * 4);
    unsigned short* h1b = (unsigned short*)alloc((size_t)(N + 1) * D_HID * 2);
    unsigned short* h2b = (unsigned short*)alloc((size_t)(N + 1) * D_OUT * 2);
    unsigned short* hgb = (unsigned short*)alloc((size_t)N * D_HID * 2);  // also ebuf
    int*   bcnt      = (int*)alloc((size_t)NB * 4);
    int*   bbase     = (int*)alloc((size_t)(NB + 1) * 4);
    int*   bcur      = (int*)alloc((size_t)NB * 4);
    unsigned short* w1s = (unsigned short*)alloc(2 * 4 * (D_HID / 16) * 64 * 8 * 2);
    unsigned short* w2s = (unsigned short*)alloc(2 * 4 * (D_OUT / 16) * 64 * 8 * 2);
    int2*  ebuf      = (int2*)hgb;   // E*8 = 12.8MB <= N*128*2 = 25.6MB; dead before agg1

    k_zero_int<<<1, 256, 0, stream>>>(bcnt, NB);
    k_bhist<<<(E + 8191) / 8192, 256, 0, stream>>>(dst, bcnt, E, NB);
    k_bscan<<<1, 256, 0, stream>>>(bcnt, bbase, bcur, NB, E);
    k_bin<<<(E + 4095) / 4096, 256, 0, stream>>>(src, dst, ebuf, bcur, E, NB);
    k_bfill<<<NB, 256, 0, stream>>>(ebuf, bbase, csr, rowstart, dinv, N, NB, E);
    k_zero_pad<<<1, 128, 0, stream>>>(h1b, h2b, N);
    k_wsplit<D_HID><<<(4 * (D_HID / 16) * 64 * 8 + 255) / 256, 256, 0, stream>>>(W1, w1s);
    k_wsplit<D_OUT><<<(4 * (D_OUT / 16) * 64 * 8 + 255) / 256, 256, 0, stream>>>(W2, w2s);

    mfma_gemm<D_HID><<<(N + 63) / 64, 256, 0, stream>>>(x, w1s, dinv, h1b, N);

    const int NBK = (N + 31) / 32;                 // node blocks per column half
    agg1_kernel<<<((NBK + 3) / 4) * 8, 256, 0, stream>>>((const uint4*)h1b, rowstart, csr,
                                                         dinv, b1, hgb, N, NBK);
    mfma_gemm_b<D_OUT><<<(N + 63) / 64, 256, 0, stream>>>(hgb, w2s, dinv, h2b, N);
    agg2_kernel<<<(N + 31) / 32, 256, 0, stream>>>((const uint4*)h2b, rowstart, csr,
                                                   dinv, b2, out, N);
}